// Round 9
// baseline (628.014 us; speedup 1.0000x reference)
//
#include <hip/hip_runtime.h>
#include <hip/hip_bf16.h>
#include <math.h>

#define B_SZ 2048
#define K_SZ 100000
#define D_SZ 50
#define BT   128      // batch rows per block (16 waves)
#define CK   64
#define STR  72        // LDS/image row stride in 2B units; 144 B = 36 dwords (non-pow2)
#define SHIFT 30.0f    // bf16 P: fp32 exponent range, no subnormal cliff (f16 failed r4)
#define LOG2E 1.4426950408889634f
#define SHIFT_L2 43.280851226668905f   // SHIFT * LOG2E
#define PSTRIDE 52
#define NCH   1563     // ceil(100000/64)
#define IMG_CH 9216    // 2B units per chunk image: 2 * 64 * STR  ([Mhi bf16 | Mt bf16])
#define IMG_BYTES ((size_t)NCH * IMG_CH * 2)
#define NSEG  18       // 1024B segments per chunk image (18432 B)

typedef short short8 __attribute__((ext_vector_type(8)));
typedef short short4v __attribute__((ext_vector_type(4)));
typedef float f32x4 __attribute__((ext_vector_type(4)));

__device__ __forceinline__ unsigned short bf16_rne(float f) {
    union { float f; unsigned int u; } v; v.f = f;
    unsigned int r = (v.u + 0x7fffu + ((v.u >> 16) & 1u)) >> 16;
    return (unsigned short)r;
}
__device__ __forceinline__ float bf16_to_f(unsigned short h) {
    union { unsigned int u; float f; } v; v.u = ((unsigned int)h) << 16;
    return v.f;
}

// async global->LDS, 16B per lane; LDS dest = wave-uniform base + lane*16 (m97/m104 semantics)
__device__ __forceinline__ void load_lds16(const void* g, void* l) {
    __builtin_amdgcn_global_load_lds(
        (const __attribute__((address_space(1))) unsigned int*)g,
        (__attribute__((address_space(3))) unsigned int*)l, 16, 0, 0);
}

// ---------------- prologue: M -> per-chunk image [Mhi bf16 | Mt bf16] ----------------
// r7 form (fastest measured): coalesced float2 reads; Mhi straight to global from regs;
// Mt transposed through LDS once, then bulk b128 copy-out.
__global__ __launch_bounds__(256)
void precompute_m(const float* __restrict__ M, unsigned short* __restrict__ img) {
    __shared__ __align__(16) unsigned short Mt[64 * STR];   // transpose scratch (9216)
    const int t = threadIdx.x;
    const int c0 = blockIdx.x;
    const int k0 = c0 * 64;
    for (int i = t; i < (64 * STR) / 2; i += 256) ((unsigned int*)Mt)[i] = 0;
    __syncthreads();
    unsigned int* gh = (unsigned int*)(img + (size_t)c0 * IMG_CH);   // 2304 dwords
    for (int i = t; i < 64 * 36; i += 256) {
        int r = i / 36, cd = i - r * 36, c = cd * 2;
        int kg = k0 + r;
        unsigned int val = 0;
        if (kg < K_SZ && c < D_SZ) {
            float2 v = *(const float2*)&M[(size_t)kg * D_SZ + c];
            val = ((unsigned int)bf16_rne(v.y) << 16) | bf16_rne(v.x);
            Mt[c * STR + r]       = (unsigned short)(val & 0xffffu);  // one-time transpose
            Mt[(c + 1) * STR + r] = (unsigned short)(val >> 16);
        }
        gh[i] = val;
    }
    __syncthreads();
    float4* go = (float4*)(img + (size_t)c0 * IMG_CH + 64 * STR);
    const float4* li = (const float4*)Mt;
    for (int i = t; i < (64 * STR) / 8; i += 256) go[i] = li[i];
}

// ---------------- hot kernel (BT=128, 16 waves) ----------------
// ph1: S[mem][batch] = Mhi . (xh + xl)^T  (2-pass x-side hi/lo split). exp in regs.
// ph2: exp(S) C-regs ARE a K=16 A-operand (C row=quad*4+r == A k-slot), emulated with the
//      verified 16x16x32 bf16 MFMA (upper k-half zero both sides).
// 16 waves share each staged chunk image -> DMA/LDS/barrier cost per unit work HALVED vs r8.
// Staging: double-buffered global_load_lds dwordx4 + per-block chunk-order rotation.
__global__ __launch_bounds__(1024, 8)
void attend_fast(const float* __restrict__ x, const unsigned short* __restrict__ img,
                 float* __restrict__ part, int slice) {
    __shared__ __align__(16) unsigned short lds[2 * IMG_CH];   // dbuf; reused as Ured after K-loop
    __shared__ float lsc[4][BT];

    const int t = threadIdx.x;
    const int w = t >> 6, lane = t & 63;
    const int quad = lane >> 4, lq = lane & 15;

    const int bid = blockIdx.x;
    const int rr = bid >> 3;
    const int split = (rr >> 4) * 8 + (bid & 7);   // same split -> same XCD (perf heuristic)
    const int xtile = rr & 15;
    const int b0 = xtile * BT;
    const int kbeg = split * slice;
    const int kend = min(kbeg + slice, K_SZ);

    const int mblk = w >> 2;       // memrow 16-tile (= ph2 k-slice), 0..3
    const int nt0 = (w & 3) * 2;   // this wave's pair of batch 16-tiles, 0..7

    // x fragments: direct global load + hi/lo bf16 split (K-loop invariant, cold path)
    short8 xh[2][2], xl[2][2];
    for (int j = 0; j < 2; ++j) {
        int row = b0 + (nt0 + j) * 16 + lq;
        const float* xr = x + (size_t)row * D_SZ;
        for (int ki = 0; ki < 2; ++ki) {
            int d0 = ki * 32 + quad * 8;
            float v[8];
#pragma unroll
            for (int e = 0; e < 8; ++e) v[e] = 0.f;
            if (d0 + 8 <= D_SZ) {
#pragma unroll
                for (int e = 0; e < 4; ++e) {
                    float2 f2 = *(const float2*)&xr[d0 + 2 * e];
                    v[2 * e] = f2.x; v[2 * e + 1] = f2.y;
                }
            } else if (d0 < D_SZ) {            // d0 == 48
                float2 f2 = *(const float2*)&xr[d0];
                v[0] = f2.x; v[1] = f2.y;
            }
            short8 sh, sl;
#pragma unroll
            for (int e = 0; e < 8; ++e) {
                unsigned short h = bf16_rne(v[e]);
                sh[e] = (short)h;
                sl[e] = (short)bf16_rne(v[e] - bf16_to_f(h));
            }
            xh[j][ki] = sh; xl[j][ki] = sl;
        }
    }

    f32x4 Uacc[2][4] = {};         // [batch tile j][d tile dt], partial over k-slice mblk
    float lac[2] = {0.f, 0.f};

    const int ci0 = kbeg >> 6;
    const int nch = (kend - kbeg + CK - 1) / CK;
    const int r0 = bid % nch;      // per-block rotation (de-phase co-resident blocks)

    // prologue DMA: rotated chunk r0 -> buf 0 (16 waves cover 18 segments)
    {
        const unsigned short* g = img + (size_t)(ci0 + r0) * IMG_CH;
        for (int seg = w; seg < NSEG; seg += 16)
            load_lds16((const unsigned int*)(g + seg * 512) + lane * 4, lds + seg * 512);
    }

    for (int i = 0; i < nch; ++i) {
        const int par = i & 1;
        unsigned short* cur = lds + par * IMG_CH;
        unsigned short* nxt = lds + (par ^ 1) * IMG_CH;

        __syncthreads();   // drains DMA of chunk i (in flight during iter i-1's compute);
                           // fences iter i-1's reads of `nxt` before we overwrite it

        if (i + 1 < nch) { // prefetch rotated chunk i+1 (overlaps with this iter's compute)
            int cc = r0 + i + 1; if (cc >= nch) cc -= nch;
            const unsigned short* g = img + (size_t)(ci0 + cc) * IMG_CH;
            for (int seg = w; seg < NSEG; seg += 16)
                load_lds16((const unsigned int*)(g + seg * 512) + lane * 4, nxt + seg * 512);
        }

        const unsigned short* Mhi = cur;
        const unsigned short* Mt  = cur + 64 * STR;

        // phase 1: S[m=memrow][n=batch], 2-pass (x-side hi/lo)
        f32x4 S[2] = {};
#pragma unroll
        for (int ki = 0; ki < 2; ++ki) {
            int aoff = (mblk * 16 + lq) * STR + ki * 32 + quad * 8;
            short8 ah = *(const short8*)&Mhi[aoff];
#pragma unroll
            for (int j = 0; j < 2; ++j) {
                S[j] = __builtin_amdgcn_mfma_f32_16x16x32_bf16(ah, xh[j][ki], S[j], 0, 0, 0);
                S[j] = __builtin_amdgcn_mfma_f32_16x16x32_bf16(ah, xl[j][ki], S[j], 0, 0, 0);
            }
        }

        // exp -> bf16 A-frags in K=16 slots 0..3 (upper half zero); packed RNE cvt
        short8 pa[2];
#pragma unroll
        for (int j = 0; j < 2; ++j) {
            float p0 = __builtin_amdgcn_exp2f(fmaf(S[j][0], LOG2E, -SHIFT_L2));
            float p1 = __builtin_amdgcn_exp2f(fmaf(S[j][1], LOG2E, -SHIFT_L2));
            float p2 = __builtin_amdgcn_exp2f(fmaf(S[j][2], LOG2E, -SHIFT_L2));
            float p3 = __builtin_amdgcn_exp2f(fmaf(S[j][3], LOG2E, -SHIFT_L2));
            lac[j] += (p0 + p1) + (p2 + p3);
            __hip_bfloat162 q01 = __float22bfloat162_rn(make_float2(p0, p1));
            __hip_bfloat162 q23 = __float22bfloat162_rn(make_float2(p2, p3));
            union { short8 s; unsigned int u[4]; } pk;
            __builtin_memcpy(&pk.u[0], &q01, 4);
            __builtin_memcpy(&pk.u[1], &q23, 4);
            pk.u[2] = 0; pk.u[3] = 0;
            pa[j] = pk.s;
        }

        // phase 2: U[batch][d] += P . M over k-slice [mblk*16, mblk*16+16)
        short8 bm[4];
#pragma unroll
        for (int dt = 0; dt < 4; ++dt) {
            short4v b4 = *(const short4v*)&Mt[(dt * 16 + lq) * STR + mblk * 16 + quad * 4];
            short8 b8;
#pragma unroll
            for (int e = 0; e < 4; ++e) { b8[e] = b4[e]; b8[e + 4] = 0; }
            bm[dt] = b8;
        }
#pragma unroll
        for (int j = 0; j < 2; ++j)
#pragma unroll
            for (int dt = 0; dt < 4; ++dt)
                Uacc[j][dt] = __builtin_amdgcn_mfma_f32_16x16x32_bf16(pa[j], bm[dt], Uacc[j][dt], 0, 0, 0);
    }

    // l reduction across quads (lane^16, lane^32 share a batch column)
    for (int j = 0; j < 2; ++j) {
        float v = lac[j];
        v += __shfl_xor(v, 16);
        v += __shfl_xor(v, 32);
        if (quad == 0) lsc[mblk][(nt0 + j) * 16 + lq] = v;
    }

    // U reduction across the 4 k-slice wave groups, in LDS (reuse lds as float [128][66])
    float* Ured = (float*)lds;
#pragma unroll
    for (int rnd = 0; rnd < 4; ++rnd) {
        __syncthreads();
        if (mblk == rnd) {
#pragma unroll
            for (int j = 0; j < 2; ++j)
#pragma unroll
                for (int dt = 0; dt < 4; ++dt)
#pragma unroll
                    for (int r4 = 0; r4 < 4; ++r4) {
                        int row = (nt0 + j) * 16 + quad * 4 + r4;
                        int col = dt * 16 + lq;
                        if (rnd == 0) Ured[row * 66 + col] = Uacc[j][dt][r4];
                        else          Ured[row * 66 + col] += Uacc[j][dt][r4];
                    }
        }
    }
    __syncthreads();

    // write partials
    float* pp = part + ((size_t)split * B_SZ + b0) * PSTRIDE;
    for (int i = t; i < BT * D_SZ; i += 1024) {
        int row = i / D_SZ, d = i - row * D_SZ;
        pp[(size_t)row * PSTRIDE + d] = Ured[row * 66 + d];
    }
    if (t < BT) {
        float Ls = lsc[0][t] + lsc[1][t] + lsc[2][t] + lsc[3][t];
        pp[(size_t)t * PSTRIDE + D_SZ] = Ls;
    }
}

// ---------------- fallback (round-2 kernel) for small ws ----------------
__global__ __launch_bounds__(512, 4)
void attend_partial_v2(const float* __restrict__ x, const float* __restrict__ M,
                       float* __restrict__ part, int slice) {
    __shared__ __align__(16) unsigned short lds[4 * 64 * STR];
    __shared__ float lsc[4][64];
    unsigned short* bufA  = lds;
    unsigned short* bufB  = lds + 64 * STR;
    unsigned short* Mc_hi = lds + 2 * 64 * STR;
    unsigned short* Mc_lo = lds + 3 * 64 * STR;

    const int t = threadIdx.x;
    const int w = t >> 6, lane = t & 63;
    const int quad = lane >> 4, lq = lane & 15;
    const int b0 = blockIdx.x * 64;
    const int split = blockIdx.y;
    const int kbeg = split * slice;
    const int kend = min(kbeg + slice, K_SZ);

    for (int i = t; i < 4 * 64 * STR; i += 512) lds[i] = 0;
    __syncthreads();
    for (int i = t; i < 64 * 25; i += 512) {
        int r = i / 25, cp = i - r * 25, c = cp * 2;
        float2 v = *(const float2*)&x[(size_t)(b0 + r) * D_SZ + c];
        unsigned short h0 = bf16_rne(v.x), h1 = bf16_rne(v.y);
        unsigned short l0 = bf16_rne(v.x - bf16_to_f(h0));
        unsigned short l1 = bf16_rne(v.y - bf16_to_f(h1));
        *(unsigned int*)&bufA[r * STR + c] = ((unsigned int)h1 << 16) | h0;
        *(unsigned int*)&bufB[r * STR + c] = ((unsigned int)l1 << 16) | l0;
    }
    __syncthreads();

    const int nt0 = (w & 1) * 2;
    const int mblk = w >> 1;
    short8 xh[2][2], xl[2][2];
    for (int j = 0; j < 2; ++j)
        for (int ki = 0; ki < 2; ++ki) {
            int off = ((nt0 + j) * 16 + lq) * STR + ki * 32 + quad * 8;
            xh[j][ki] = *(const short8*)&bufA[off];
            xl[j][ki] = *(const short8*)&bufB[off];
        }

    f32x4 Uacc[2] = {};
    float lac[2] = {0.f, 0.f};

    for (int k0 = kbeg; k0 < kend; k0 += CK) {
        __syncthreads();
        for (int i = t; i < 64 * 25; i += 512) {
            int r = i / 25, cp = i - r * 25, c = cp * 2;
            int kg = k0 + r;
            float2 v = make_float2(0.f, 0.f);
            if (kg < kend) v = *(const float2*)&M[(size_t)kg * D_SZ + c];
            unsigned short h0 = bf16_rne(v.x), h1 = bf16_rne(v.y);
            unsigned short l0 = bf16_rne(v.x - bf16_to_f(h0));
            unsigned short l1 = bf16_rne(v.y - bf16_to_f(h1));
            *(unsigned int*)&Mc_hi[r * STR + c] = ((unsigned int)h1 << 16) | h0;
            *(unsigned int*)&Mc_lo[r * STR + c] = ((unsigned int)l1 << 16) | l0;
            bufB[c * STR + r] = h0;
            bufB[(c + 1) * STR + r] = h1;
        }
        __syncthreads();

        f32x4 S[2] = {};
        for (int ki = 0; ki < 2; ++ki) {
            int aoff = (mblk * 16 + lq) * STR + ki * 32 + quad * 8;
            short8 ah = *(const short8*)&Mc_hi[aoff];
            short8 al = *(const short8*)&Mc_lo[aoff];
            for (int j = 0; j < 2; ++j) {
                S[j] = __builtin_amdgcn_mfma_f32_16x16x32_bf16(ah, xh[j][ki], S[j], 0, 0, 0);
                S[j] = __builtin_amdgcn_mfma_f32_16x16x32_bf16(ah, xl[j][ki], S[j], 0, 0, 0);
                S[j] = __builtin_amdgcn_mfma_f32_16x16x32_bf16(al, xh[j][ki], S[j], 0, 0, 0);
            }
        }
        for (int j = 0; j < 2; ++j) {
            unsigned short pb4[4];
#pragma unroll
            for (int r4 = 0; r4 < 4; ++r4) {
                float p = __expf(S[j][r4] - SHIFT);
                lac[j] += p;
                pb4[r4] = bf16_rne(p);
            }
            int b = (nt0 + j) * 16 + lq;
            int n0 = mblk * 16 + quad * 4;
            *(unsigned int*)&bufA[b * STR + n0]     = ((unsigned int)pb4[1] << 16) | pb4[0];
            *(unsigned int*)&bufA[b * STR + n0 + 2] = ((unsigned int)pb4[3] << 16) | pb4[2];
        }
        __syncthreads();
        for (int ki = 0; ki < 2; ++ki) {
            int poff = (mblk * 16 + lq) * STR + ki * 32 + quad * 8;
            short8 ap = *(const short8*)&bufA[poff];
            for (int j = 0; j < 2; ++j) {
                int doff = ((nt0 + j) * 16 + lq) * STR + ki * 32 + quad * 8;
                short8 bm = *(const short8*)&bufB[doff];
                Uacc[j] = __builtin_amdgcn_mfma_f32_16x16x32_bf16(ap, bm, Uacc[j], 0, 0, 0);
            }
        }
    }

    for (int j = 0; j < 2; ++j) {
        float v = lac[j];
        v += __shfl_xor(v, 16);
        v += __shfl_xor(v, 32);
        if (quad == 0) lsc[mblk][(nt0 + j) * 16 + lq] = v;
    }
    __syncthreads();
    float* pp = part + ((size_t)split * B_SZ + b0) * PSTRIDE;
    for (int j = 0; j < 2; ++j) {
        int d = (nt0 + j) * 16 + lq;
        if (d < D_SZ) {
#pragma unroll
            for (int r4 = 0; r4 < 4; ++r4) {
                int b = mblk * 16 + quad * 4 + r4;
                pp[(size_t)b * PSTRIDE + d] = Uacc[j][r4];
            }
        }
    }
    if (t < 64) {
        float Ls = lsc[0][t] + lsc[1][t] + lsc[2][t] + lsc[3][t];
        pp[(size_t)t * PSTRIDE + D_SZ] = Ls;
    }
}

__global__ __launch_bounds__(64)
void combine(const float* __restrict__ x, const float* __restrict__ part,
             float* __restrict__ out, int nsplit) {
    const int b = blockIdx.x;
    const int t = threadIdx.x;
    float L = 0.f;
    for (int s = 0; s < nsplit; ++s)
        L += part[((size_t)s * B_SZ + b) * PSTRIDE + D_SZ];
    if (t < D_SZ) {
        float acc = 0.f;
        for (int s = 0; s < nsplit; ++s)
            acc += part[((size_t)s * B_SZ + b) * PSTRIDE + t];
        out[(size_t)b * (2 * D_SZ) + t] = x[(size_t)b * D_SZ + t];
        out[(size_t)b * (2 * D_SZ) + D_SZ + t] = acc / L;
    }
}

extern "C" void kernel_launch(void* const* d_in, const int* in_sizes, int n_in,
                              void* d_out, int out_size, void* d_ws, size_t ws_size,
                              hipStream_t stream) {
    const float* x = (const float*)d_in[0];
    const float* M = (const float*)d_in[1];
    float* out = (float*)d_out;
    const size_t per_split = (size_t)B_SZ * PSTRIDE * sizeof(float);

    if (ws_size >= IMG_BYTES + 8 * per_split) {
        unsigned short* img = (unsigned short*)d_ws;
        float* part = (float*)((char*)d_ws + IMG_BYTES);
        int ns = (int)((ws_size - IMG_BYTES) / per_split);
        if (ns > 32) ns = 32;
        ns &= ~7;                                          // multiple of 8 for XCD swizzle
        int slice = (((K_SZ + ns - 1) / ns) + 63) & ~63;   // 64-aligned splits
        precompute_m<<<NCH, 256, 0, stream>>>(M, img);
        attend_fast<<<(B_SZ / BT) * ns, 1024, 0, stream>>>(x, img, part, slice);
        combine<<<B_SZ, 64, 0, stream>>>(x, part, out, ns);
    } else {
        float* part = (float*)d_ws;
        int ns = (int)(ws_size / per_split);
        if (ns > 32) ns = 32;
        if (ns < 1) ns = 1;
        int slice = (K_SZ + ns - 1) / ns;
        dim3 gridA(B_SZ / 64, ns);
        attend_partial_v2<<<gridA, 512, 0, stream>>>(x, M, part, slice);
        combine<<<B_SZ, 64, 0, stream>>>(x, part, out, ns);
    }
}

// Round 11
// 349.753 us; speedup vs baseline: 1.7956x; 1.7956x over previous
//
#include <hip/hip_runtime.h>
#include <hip/hip_bf16.h>
#include <math.h>

#define B_SZ 2048
#define K_SZ 100000
#define D_SZ 50
#define BT   64       // batch rows per block (8 waves, 512 thr) — do NOT grow to 128/1024thr:
                      // r9 measured VGPR starvation (32 alloc vs ~60 need) -> 1.9GB scratch spill
#define CK   64
#define STR  72        // LDS/image row stride in 2B units; 144 B = 36 dwords (non-pow2)
#define SHIFT 30.0f    // bf16 P: fp32 exponent range, no subnormal cliff (f16 failed r4)
#define LOG2E 1.4426950408889634f
#define SHIFT_L2 43.280851226668905f   // SHIFT * LOG2E
#define PSTRIDE 52
#define NCH   1563     // ceil(100000/64)
#define IMG_CH 9216    // 2B units per chunk image: 2 * 64 * STR  ([Mhi bf16 | Mt bf16])
#define IMG_BYTES ((size_t)NCH * IMG_CH * 2)
#define NSEG  18       // 1024B segments per chunk image (18432 B)

typedef short short8 __attribute__((ext_vector_type(8)));
typedef short short4v __attribute__((ext_vector_type(4)));
typedef float f32x4 __attribute__((ext_vector_type(4)));

__device__ __forceinline__ unsigned short bf16_rne(float f) {
    union { float f; unsigned int u; } v; v.f = f;
    unsigned int r = (v.u + 0x7fffu + ((v.u >> 16) & 1u)) >> 16;
    return (unsigned short)r;
}
__device__ __forceinline__ float bf16_to_f(unsigned short h) {
    union { unsigned int u; float f; } v; v.u = ((unsigned int)h) << 16;
    return v.f;
}

// async global->LDS, 16B per lane; LDS dest = wave-uniform base + lane*16 (m97/m104 semantics)
__device__ __forceinline__ void load_lds16(const void* g, void* l) {
    __builtin_amdgcn_global_load_lds(
        (const __attribute__((address_space(1))) unsigned int*)g,
        (__attribute__((address_space(3))) unsigned int*)l, 16, 0, 0);
}

// ---------------- prologue: M -> per-chunk image [Mhi bf16 | Mt bf16] ----------------
// r7 version VERBATIM (passed post-timing tripwires in r7 and r8-equivalent runs; the r10
// rewrite failed replay-only — reverted on evidence). + trailing __threadfence release.
__global__ __launch_bounds__(256)
void precompute_m(const float* __restrict__ M, unsigned short* __restrict__ img) {
    __shared__ __align__(16) unsigned short Mt[64 * STR];   // transpose scratch (9216)
    const int t = threadIdx.x;
    const int c0 = blockIdx.x;
    const int k0 = c0 * 64;
    for (int i = t; i < (64 * STR) / 2; i += 256) ((unsigned int*)Mt)[i] = 0;
    __syncthreads();
    unsigned int* gh = (unsigned int*)(img + (size_t)c0 * IMG_CH);   // 2304 dwords
    for (int i = t; i < 64 * 36; i += 256) {
        int r = i / 36, cd = i - r * 36, c = cd * 2;
        int kg = k0 + r;
        unsigned int val = 0;
        if (kg < K_SZ && c < D_SZ) {
            float2 v = *(const float2*)&M[(size_t)kg * D_SZ + c];
            val = ((unsigned int)bf16_rne(v.y) << 16) | bf16_rne(v.x);
            Mt[c * STR + r]       = (unsigned short)(val & 0xffffu);  // one-time transpose
            Mt[(c + 1) * STR + r] = (unsigned short)(val >> 16);
        }
        gh[i] = val;
    }
    __syncthreads();
    float4* go = (float4*)(img + (size_t)c0 * IMG_CH + 64 * STR);
    const float4* li = (const float4*)Mt;
    for (int i = t; i < (64 * STR) / 8; i += 256) go[i] = li[i];
    __threadfence();   // device-scope release of img before block exit
}

// ---------------- hot kernel (r8-proven: 512 thr, BT=64, 60 VGPR, 4 blocks/CU) ----------------
// ph1: S[mem][batch] = Mhi . (xh + xl)^T  (2-pass x-side hi/lo split). exp in regs.
// ph2: exp(S) C-regs ARE a K=16 A-operand (C row=quad*4+r == A k-slot), emulated with the
//      verified 16x16x32 bf16 MFMA (upper k-half zero both sides).
// Staging: double-buffered global_load_lds dwordx4 + per-block chunk-order rotation.
// Hardening: explicit s_waitcnt(0) before the K-loop barrier (full DMA drain even if the
//      compiler's implicit vmcnt(0)-before-s_barrier is ever elided).
__global__ __launch_bounds__(512, 4)
void attend_fast(const float* __restrict__ x, const unsigned short* __restrict__ img,
                 float* __restrict__ part, int slice) {
    __shared__ __align__(16) unsigned short lds[2 * IMG_CH];   // dbuf; buf0 reused as Ured
    __shared__ float lsc[4][64];

    const int t = threadIdx.x;
    const int w = t >> 6, lane = t & 63;
    const int quad = lane >> 4, lq = lane & 15;

    const int bid = blockIdx.x;
    const int rr = bid >> 3;
    const int split = (rr >> 5) * 8 + (bid & 7);   // same split -> same XCD (perf heuristic)
    const int xtile = rr & 31;
    const int b0 = xtile * BT;
    const int kbeg = split * slice;
    const int kend = min(kbeg + slice, K_SZ);

    const int nt0 = (w & 1) * 2;   // this wave's pair of batch 16-tiles
    const int mblk = w >> 1;       // this wave's memrow 16-tile (= its ph2 k-slice)

    // x fragments: direct global load + hi/lo bf16 split (K-loop invariant, cold path)
    short8 xh[2][2], xl[2][2];
    for (int j = 0; j < 2; ++j) {
        int row = b0 + (nt0 + j) * 16 + lq;
        const float* xr = x + (size_t)row * D_SZ;
        for (int ki = 0; ki < 2; ++ki) {
            int d0 = ki * 32 + quad * 8;
            float v[8];
#pragma unroll
            for (int e = 0; e < 8; ++e) v[e] = 0.f;
            if (d0 + 8 <= D_SZ) {
#pragma unroll
                for (int e = 0; e < 4; ++e) {
                    float2 f2 = *(const float2*)&xr[d0 + 2 * e];
                    v[2 * e] = f2.x; v[2 * e + 1] = f2.y;
                }
            } else if (d0 < D_SZ) {            // d0 == 48
                float2 f2 = *(const float2*)&xr[d0];
                v[0] = f2.x; v[1] = f2.y;
            }
            short8 sh, sl;
#pragma unroll
            for (int e = 0; e < 8; ++e) {
                unsigned short h = bf16_rne(v[e]);
                sh[e] = (short)h;
                sl[e] = (short)bf16_rne(v[e] - bf16_to_f(h));
            }
            xh[j][ki] = sh; xl[j][ki] = sl;
        }
    }

    f32x4 Uacc[2][4] = {};         // [batch tile j][d tile dt], partial over k-slice mblk
    float lac[2] = {0.f, 0.f};

    const int ci0 = kbeg >> 6;
    const int nch = (kend - kbeg + CK - 1) / CK;
    const int r0 = bid % nch;      // per-block rotation (de-phase co-resident blocks)

    // prologue DMA: rotated chunk r0 -> buf 0
    {
        const unsigned short* g = img + (size_t)(ci0 + r0) * IMG_CH;
        for (int seg = w; seg < NSEG; seg += 8)
            load_lds16((const unsigned int*)(g + seg * 512) + lane * 4, lds + seg * 512);
    }

    for (int i = 0; i < nch; ++i) {
        const int par = i & 1;
        unsigned short* cur = lds + par * IMG_CH;
        unsigned short* nxt = lds + (par ^ 1) * IMG_CH;

        __builtin_amdgcn_s_waitcnt(0);   // explicit full drain (vm+lgkm) — DMA hardening
        __syncthreads();   // drains DMA of chunk i (in flight during iter i-1's compute);
                           // fences iter i-1's reads of `nxt` before we overwrite it

        if (i + 1 < nch) { // prefetch rotated chunk i+1 (overlaps with this iter's compute)
            int cc = r0 + i + 1; if (cc >= nch) cc -= nch;
            const unsigned short* g = img + (size_t)(ci0 + cc) * IMG_CH;
            for (int seg = w; seg < NSEG; seg += 8)
                load_lds16((const unsigned int*)(g + seg * 512) + lane * 4, nxt + seg * 512);
        }

        const unsigned short* Mhi = cur;
        const unsigned short* Mt  = cur + 64 * STR;

        // phase 1: S[m=memrow][n=batch], 2-pass (x-side hi/lo)
        f32x4 S[2] = {};
#pragma unroll
        for (int ki = 0; ki < 2; ++ki) {
            int aoff = (mblk * 16 + lq) * STR + ki * 32 + quad * 8;
            short8 ah = *(const short8*)&Mhi[aoff];
#pragma unroll
            for (int j = 0; j < 2; ++j) {
                S[j] = __builtin_amdgcn_mfma_f32_16x16x32_bf16(ah, xh[j][ki], S[j], 0, 0, 0);
                S[j] = __builtin_amdgcn_mfma_f32_16x16x32_bf16(ah, xl[j][ki], S[j], 0, 0, 0);
            }
        }

        // exp -> bf16 A-frags in K=16 slots 0..3 (upper half zero); packed RNE cvt
        short8 pa[2];
#pragma unroll
        for (int j = 0; j < 2; ++j) {
            float p0 = __builtin_amdgcn_exp2f(fmaf(S[j][0], LOG2E, -SHIFT_L2));
            float p1 = __builtin_amdgcn_exp2f(fmaf(S[j][1], LOG2E, -SHIFT_L2));
            float p2 = __builtin_amdgcn_exp2f(fmaf(S[j][2], LOG2E, -SHIFT_L2));
            float p3 = __builtin_amdgcn_exp2f(fmaf(S[j][3], LOG2E, -SHIFT_L2));
            lac[j] += (p0 + p1) + (p2 + p3);
            __hip_bfloat162 q01 = __float22bfloat162_rn(make_float2(p0, p1));
            __hip_bfloat162 q23 = __float22bfloat162_rn(make_float2(p2, p3));
            union { short8 s; unsigned int u[4]; } pk;
            __builtin_memcpy(&pk.u[0], &q01, 4);
            __builtin_memcpy(&pk.u[1], &q23, 4);
            pk.u[2] = 0; pk.u[3] = 0;
            pa[j] = pk.s;
        }

        // phase 2: U[batch][d] += P . M over k-slice [mblk*16, mblk*16+16)
        short8 bm[4];
#pragma unroll
        for (int dt = 0; dt < 4; ++dt) {
            short4v b4 = *(const short4v*)&Mt[(dt * 16 + lq) * STR + mblk * 16 + quad * 4];
            short8 b8;
#pragma unroll
            for (int e = 0; e < 4; ++e) { b8[e] = b4[e]; b8[e + 4] = 0; }
            bm[dt] = b8;
        }
#pragma unroll
        for (int j = 0; j < 2; ++j)
#pragma unroll
            for (int dt = 0; dt < 4; ++dt)
                Uacc[j][dt] = __builtin_amdgcn_mfma_f32_16x16x32_bf16(pa[j], bm[dt], Uacc[j][dt], 0, 0, 0);
    }

    // l reduction across quads (lane^16, lane^32 share a batch column)
    for (int j = 0; j < 2; ++j) {
        float v = lac[j];
        v += __shfl_xor(v, 16);
        v += __shfl_xor(v, 32);
        if (quad == 0) lsc[mblk][(nt0 + j) * 16 + lq] = v;
    }

    // U reduction across the 4 k-slice waves, in LDS (reuse buf0 as float [64][66])
    float* Ured = (float*)lds;
#pragma unroll
    for (int rnd = 0; rnd < 4; ++rnd) {
        __syncthreads();
        if (mblk == rnd) {
#pragma unroll
            for (int j = 0; j < 2; ++j)
#pragma unroll
                for (int dt = 0; dt < 4; ++dt)
#pragma unroll
                    for (int r4 = 0; r4 < 4; ++r4) {
                        int row = (nt0 + j) * 16 + quad * 4 + r4;
                        int col = dt * 16 + lq;
                        if (rnd == 0) Ured[row * 66 + col] = Uacc[j][dt][r4];
                        else          Ured[row * 66 + col] += Uacc[j][dt][r4];
                    }
        }
    }
    __syncthreads();

    // write partials
    float* pp = part + ((size_t)split * B_SZ + b0) * PSTRIDE;
    for (int i = t; i < 64 * D_SZ; i += 512) {
        int row = i / D_SZ, d = i - row * D_SZ;
        pp[(size_t)row * PSTRIDE + d] = Ured[row * 66 + d];
    }
    if (t < 64) {
        float Ls = lsc[0][t] + lsc[1][t] + lsc[2][t] + lsc[3][t];
        pp[(size_t)t * PSTRIDE + D_SZ] = Ls;
    }
}

// ---------------- fallback (round-2 kernel) for small ws ----------------
__global__ __launch_bounds__(512, 4)
void attend_partial_v2(const float* __restrict__ x, const float* __restrict__ M,
                       float* __restrict__ part, int slice) {
    __shared__ __align__(16) unsigned short lds[4 * 64 * STR];
    __shared__ float lsc[4][64];
    unsigned short* bufA  = lds;
    unsigned short* bufB  = lds + 64 * STR;
    unsigned short* Mc_hi = lds + 2 * 64 * STR;
    unsigned short* Mc_lo = lds + 3 * 64 * STR;

    const int t = threadIdx.x;
    const int w = t >> 6, lane = t & 63;
    const int quad = lane >> 4, lq = lane & 15;
    const int b0 = blockIdx.x * 64;
    const int split = blockIdx.y;
    const int kbeg = split * slice;
    const int kend = min(kbeg + slice, K_SZ);

    for (int i = t; i < 4 * 64 * STR; i += 512) lds[i] = 0;
    __syncthreads();
    for (int i = t; i < 64 * 25; i += 512) {
        int r = i / 25, cp = i - r * 25, c = cp * 2;
        float2 v = *(const float2*)&x[(size_t)(b0 + r) * D_SZ + c];
        unsigned short h0 = bf16_rne(v.x), h1 = bf16_rne(v.y);
        unsigned short l0 = bf16_rne(v.x - bf16_to_f(h0));
        unsigned short l1 = bf16_rne(v.y - bf16_to_f(h1));
        *(unsigned int*)&bufA[r * STR + c] = ((unsigned int)h1 << 16) | h0;
        *(unsigned int*)&bufB[r * STR + c] = ((unsigned int)l1 << 16) | l0;
    }
    __syncthreads();

    const int nt0 = (w & 1) * 2;
    const int mblk = w >> 1;
    short8 xh[2][2], xl[2][2];
    for (int j = 0; j < 2; ++j)
        for (int ki = 0; ki < 2; ++ki) {
            int off = ((nt0 + j) * 16 + lq) * STR + ki * 32 + quad * 8;
            xh[j][ki] = *(const short8*)&bufA[off];
            xl[j][ki] = *(const short8*)&bufB[off];
        }

    f32x4 Uacc[2] = {};
    float lac[2] = {0.f, 0.f};

    for (int k0 = kbeg; k0 < kend; k0 += CK) {
        __syncthreads();
        for (int i = t; i < 64 * 25; i += 512) {
            int r = i / 25, cp = i - r * 25, c = cp * 2;
            int kg = k0 + r;
            float2 v = make_float2(0.f, 0.f);
            if (kg < kend) v = *(const float2*)&M[(size_t)kg * D_SZ + c];
            unsigned short h0 = bf16_rne(v.x), h1 = bf16_rne(v.y);
            unsigned short l0 = bf16_rne(v.x - bf16_to_f(h0));
            unsigned short l1 = bf16_rne(v.y - bf16_to_f(h1));
            *(unsigned int*)&Mc_hi[r * STR + c] = ((unsigned int)h1 << 16) | h0;
            *(unsigned int*)&Mc_lo[r * STR + c] = ((unsigned int)l1 << 16) | l0;
            bufB[c * STR + r] = h0;
            bufB[(c + 1) * STR + r] = h1;
        }
        __syncthreads();

        f32x4 S[2] = {};
        for (int ki = 0; ki < 2; ++ki) {
            int aoff = (mblk * 16 + lq) * STR + ki * 32 + quad * 8;
            short8 ah = *(const short8*)&Mc_hi[aoff];
            short8 al = *(const short8*)&Mc_lo[aoff];
            for (int j = 0; j < 2; ++j) {
                S[j] = __builtin_amdgcn_mfma_f32_16x16x32_bf16(ah, xh[j][ki], S[j], 0, 0, 0);
                S[j] = __builtin_amdgcn_mfma_f32_16x16x32_bf16(ah, xl[j][ki], S[j], 0, 0, 0);
                S[j] = __builtin_amdgcn_mfma_f32_16x16x32_bf16(al, xh[j][ki], S[j], 0, 0, 0);
            }
        }
        for (int j = 0; j < 2; ++j) {
            unsigned short pb4[4];
#pragma unroll
            for (int r4 = 0; r4 < 4; ++r4) {
                float p = __expf(S[j][r4] - SHIFT);
                lac[j] += p;
                pb4[r4] = bf16_rne(p);
            }
            int b = (nt0 + j) * 16 + lq;
            int n0 = mblk * 16 + quad * 4;
            *(unsigned int*)&bufA[b * STR + n0]     = ((unsigned int)pb4[1] << 16) | pb4[0];
            *(unsigned int*)&bufA[b * STR + n0 + 2] = ((unsigned int)pb4[3] << 16) | pb4[2];
        }
        __syncthreads();
        for (int ki = 0; ki < 2; ++ki) {
            int poff = (mblk * 16 + lq) * STR + ki * 32 + quad * 8;
            short8 ap = *(const short8*)&bufA[poff];
            for (int j = 0; j < 2; ++j) {
                int doff = ((nt0 + j) * 16 + lq) * STR + ki * 32 + quad * 8;
                short8 bm = *(const short8*)&bufB[doff];
                Uacc[j] = __builtin_amdgcn_mfma_f32_16x16x32_bf16(ap, bm, Uacc[j], 0, 0, 0);
            }
        }
    }

    for (int j = 0; j < 2; ++j) {
        float v = lac[j];
        v += __shfl_xor(v, 16);
        v += __shfl_xor(v, 32);
        if (quad == 0) lsc[mblk][(nt0 + j) * 16 + lq] = v;
    }
    __syncthreads();
    float* pp = part + ((size_t)split * B_SZ + b0) * PSTRIDE;
    for (int j = 0; j < 2; ++j) {
        int d = (nt0 + j) * 16 + lq;
        if (d < D_SZ) {
#pragma unroll
            for (int r4 = 0; r4 < 4; ++r4) {
                int b = mblk * 16 + quad * 4 + r4;
                pp[(size_t)b * PSTRIDE + d] = Uacc[j][r4];
            }
        }
    }
    if (t < 64) {
        float Ls = lsc[0][t] + lsc[1][t] + lsc[2][t] + lsc[3][t];
        pp[(size_t)t * PSTRIDE + D_SZ] = Ls;
    }
}

__global__ __launch_bounds__(64)
void combine(const float* __restrict__ x, const float* __restrict__ part,
             float* __restrict__ out, int nsplit) {
    const int b = blockIdx.x;
    const int t = threadIdx.x;
    float L = 0.f;
    for (int s = 0; s < nsplit; ++s)
        L += part[((size_t)s * B_SZ + b) * PSTRIDE + D_SZ];
    if (t < D_SZ) {
        float acc = 0.f;
        for (int s = 0; s < nsplit; ++s)
            acc += part[((size_t)s * B_SZ + b) * PSTRIDE + t];
        out[(size_t)b * (2 * D_SZ) + t] = x[(size_t)b * D_SZ + t];
        out[(size_t)b * (2 * D_SZ) + D_SZ + t] = acc / L;
    }
}

extern "C" void kernel_launch(void* const* d_in, const int* in_sizes, int n_in,
                              void* d_out, int out_size, void* d_ws, size_t ws_size,
                              hipStream_t stream) {
    const float* x = (const float*)d_in[0];
    const float* M = (const float*)d_in[1];
    float* out = (float*)d_out;
    const size_t per_split = (size_t)B_SZ * PSTRIDE * sizeof(float);

    if (ws_size >= IMG_BYTES + 8 * per_split) {
        unsigned short* img = (unsigned short*)d_ws;
        float* part = (float*)((char*)d_ws + IMG_BYTES);
        int ns = (int)((ws_size - IMG_BYTES) / per_split);
        if (ns > 32) ns = 32;
        ns &= ~7;                                          // multiple of 8 for XCD swizzle
        int slice = (((K_SZ + ns - 1) / ns) + 63) & ~63;   // 64-aligned splits
        precompute_m<<<NCH, 256, 0, stream>>>(M, img);
        attend_fast<<<32 * ns, 512, 0, stream>>>(x, img, part, slice);
        combine<<<B_SZ, 64, 0, stream>>>(x, part, out, ns);
    } else {
        float* part = (float*)d_ws;
        int ns = (int)(ws_size / per_split);
        if (ns > 32) ns = 32;
        if (ns < 1) ns = 1;
        int slice = (K_SZ + ns - 1) / ns;
        dim3 gridA(B_SZ / 64, ns);
        attend_partial_v2<<<gridA, 512, 0, stream>>>(x, M, part, slice);
        combine<<<B_SZ, 64, 0, stream>>>(x, part, out, ns);
    }
}

// Round 12
// 198.948 us; speedup vs baseline: 3.1567x; 1.7580x over previous
//
#include <hip/hip_runtime.h>
#include <hip/hip_bf16.h>
#include <math.h>

#define B_SZ 2048
#define K_SZ 100000
#define D_SZ 50
#define BT   64       // batch rows per block (8 waves, 512 thr) — do NOT grow to 128/1024thr:
                      // r9 measured VGPR starvation (32 alloc vs ~60 need) -> 1.9GB scratch spill
#define CK   64
#define STR  72        // LDS/image row stride in 2B units; 144 B = 36 dwords (non-pow2)
#define SHIFT 30.0f    // bf16 P: fp32 exponent range, no subnormal cliff (f16 failed r4)
#define LOG2E 1.4426950408889634f
#define SHIFT_L2 43.280851226668905f   // SHIFT * LOG2E
#define PSTRIDE 52
#define NCH   1563     // ceil(100000/64)
#define IMG_CH 9216    // 2B units per chunk image: 2 * 64 * STR  ([Mhi bf16 | Mt bf16])
#define IMG_BYTES ((size_t)NCH * IMG_CH * 2)
#define NSEG  18       // 1024B segments per chunk image (18432 B)

typedef short short8 __attribute__((ext_vector_type(8)));
typedef short short4v __attribute__((ext_vector_type(4)));
typedef float f32x4 __attribute__((ext_vector_type(4)));

__device__ __forceinline__ unsigned short bf16_rne(float f) {
    union { float f; unsigned int u; } v; v.f = f;
    unsigned int r = (v.u + 0x7fffu + ((v.u >> 16) & 1u)) >> 16;
    return (unsigned short)r;
}
__device__ __forceinline__ float bf16_to_f(unsigned short h) {
    union { unsigned int u; float f; } v; v.u = ((unsigned int)h) << 16;
    return v.f;
}

// async global->LDS, 16B per lane; LDS dest = wave-uniform base + lane*16 (m97/m104 semantics)
__device__ __forceinline__ void load_lds16(const void* g, void* l) {
    __builtin_amdgcn_global_load_lds(
        (const __attribute__((address_space(1))) unsigned int*)g,
        (__attribute__((address_space(3))) unsigned int*)l, 16, 0, 0);
}

// ---------------- prologue: M -> per-chunk image [Mhi bf16 | Mt bf16] ----------------
// r7 version VERBATIM (passed post-timing tripwires r7/r8/r11).
// NO __threadfence here: r11 measured it at +120us (agent-scope release = per-block L2
// writeback, 1563 blocks serialized on the wbl2 path). Kernel-boundary coherence is
// handled by the runtime's inter-dispatch cache ops.
__global__ __launch_bounds__(256)
void precompute_m(const float* __restrict__ M, unsigned short* __restrict__ img) {
    __shared__ __align__(16) unsigned short Mt[64 * STR];   // transpose scratch (9216)
    const int t = threadIdx.x;
    const int c0 = blockIdx.x;
    const int k0 = c0 * 64;
    for (int i = t; i < (64 * STR) / 2; i += 256) ((unsigned int*)Mt)[i] = 0;
    __syncthreads();
    unsigned int* gh = (unsigned int*)(img + (size_t)c0 * IMG_CH);   // 2304 dwords
    for (int i = t; i < 64 * 36; i += 256) {
        int r = i / 36, cd = i - r * 36, c = cd * 2;
        int kg = k0 + r;
        unsigned int val = 0;
        if (kg < K_SZ && c < D_SZ) {
            float2 v = *(const float2*)&M[(size_t)kg * D_SZ + c];
            val = ((unsigned int)bf16_rne(v.y) << 16) | bf16_rne(v.x);
            Mt[c * STR + r]       = (unsigned short)(val & 0xffffu);  // one-time transpose
            Mt[(c + 1) * STR + r] = (unsigned short)(val >> 16);
        }
        gh[i] = val;
    }
    __syncthreads();
    float4* go = (float4*)(img + (size_t)c0 * IMG_CH + 64 * STR);
    const float4* li = (const float4*)Mt;
    for (int i = t; i < (64 * STR) / 8; i += 256) go[i] = li[i];
}

// ---------------- hot kernel (r8-proven: 512 thr, BT=64, 60 VGPR, 4 blocks/CU) ----------------
// ph1: S[mem][batch] = Mhi . (xh + xl)^T  (2-pass x-side hi/lo split). exp in regs.
// ph2: exp(S) C-regs ARE a K=16 A-operand (C row=quad*4+r == A k-slot), emulated with the
//      verified 16x16x32 bf16 MFMA (upper k-half zero both sides).
// Staging: double-buffered global_load_lds dwordx4 + per-block chunk-order rotation.
// Hardening: explicit s_waitcnt(0) before the K-loop barrier (present in r11's passing run;
//      redundant with compiler's pre-barrier drain, perf-neutral).
__global__ __launch_bounds__(512, 4)
void attend_fast(const float* __restrict__ x, const unsigned short* __restrict__ img,
                 float* __restrict__ part, int slice) {
    __shared__ __align__(16) unsigned short lds[2 * IMG_CH];   // dbuf; buf0 reused as Ured
    __shared__ float lsc[4][64];

    const int t = threadIdx.x;
    const int w = t >> 6, lane = t & 63;
    const int quad = lane >> 4, lq = lane & 15;

    const int bid = blockIdx.x;
    const int rr = bid >> 3;
    const int split = (rr >> 5) * 8 + (bid & 7);   // same split -> same XCD (perf heuristic)
    const int xtile = rr & 31;
    const int b0 = xtile * BT;
    const int kbeg = split * slice;
    const int kend = min(kbeg + slice, K_SZ);

    const int nt0 = (w & 1) * 2;   // this wave's pair of batch 16-tiles
    const int mblk = w >> 1;       // this wave's memrow 16-tile (= its ph2 k-slice)

    // x fragments: direct global load + hi/lo bf16 split (K-loop invariant, cold path)
    short8 xh[2][2], xl[2][2];
    for (int j = 0; j < 2; ++j) {
        int row = b0 + (nt0 + j) * 16 + lq;
        const float* xr = x + (size_t)row * D_SZ;
        for (int ki = 0; ki < 2; ++ki) {
            int d0 = ki * 32 + quad * 8;
            float v[8];
#pragma unroll
            for (int e = 0; e < 8; ++e) v[e] = 0.f;
            if (d0 + 8 <= D_SZ) {
#pragma unroll
                for (int e = 0; e < 4; ++e) {
                    float2 f2 = *(const float2*)&xr[d0 + 2 * e];
                    v[2 * e] = f2.x; v[2 * e + 1] = f2.y;
                }
            } else if (d0 < D_SZ) {            // d0 == 48
                float2 f2 = *(const float2*)&xr[d0];
                v[0] = f2.x; v[1] = f2.y;
            }
            short8 sh, sl;
#pragma unroll
            for (int e = 0; e < 8; ++e) {
                unsigned short h = bf16_rne(v[e]);
                sh[e] = (short)h;
                sl[e] = (short)bf16_rne(v[e] - bf16_to_f(h));
            }
            xh[j][ki] = sh; xl[j][ki] = sl;
        }
    }

    f32x4 Uacc[2][4] = {};         // [batch tile j][d tile dt], partial over k-slice mblk
    float lac[2] = {0.f, 0.f};

    const int ci0 = kbeg >> 6;
    const int nch = (kend - kbeg + CK - 1) / CK;
    const int r0 = bid % nch;      // per-block rotation (de-phase co-resident blocks)

    // prologue DMA: rotated chunk r0 -> buf 0
    {
        const unsigned short* g = img + (size_t)(ci0 + r0) * IMG_CH;
        for (int seg = w; seg < NSEG; seg += 8)
            load_lds16((const unsigned int*)(g + seg * 512) + lane * 4, lds + seg * 512);
    }

    for (int i = 0; i < nch; ++i) {
        const int par = i & 1;
        unsigned short* cur = lds + par * IMG_CH;
        unsigned short* nxt = lds + (par ^ 1) * IMG_CH;

        __builtin_amdgcn_s_waitcnt(0);   // explicit full drain (vm+lgkm) — DMA hardening
        __syncthreads();   // drains DMA of chunk i (in flight during iter i-1's compute);
                           // fences iter i-1's reads of `nxt` before we overwrite it

        if (i + 1 < nch) { // prefetch rotated chunk i+1 (overlaps with this iter's compute)
            int cc = r0 + i + 1; if (cc >= nch) cc -= nch;
            const unsigned short* g = img + (size_t)(ci0 + cc) * IMG_CH;
            for (int seg = w; seg < NSEG; seg += 8)
                load_lds16((const unsigned int*)(g + seg * 512) + lane * 4, nxt + seg * 512);
        }

        const unsigned short* Mhi = cur;
        const unsigned short* Mt  = cur + 64 * STR;

        // phase 1: S[m=memrow][n=batch], 2-pass (x-side hi/lo)
        f32x4 S[2] = {};
#pragma unroll
        for (int ki = 0; ki < 2; ++ki) {
            int aoff = (mblk * 16 + lq) * STR + ki * 32 + quad * 8;
            short8 ah = *(const short8*)&Mhi[aoff];
#pragma unroll
            for (int j = 0; j < 2; ++j) {
                S[j] = __builtin_amdgcn_mfma_f32_16x16x32_bf16(ah, xh[j][ki], S[j], 0, 0, 0);
                S[j] = __builtin_amdgcn_mfma_f32_16x16x32_bf16(ah, xl[j][ki], S[j], 0, 0, 0);
            }
        }

        // exp -> bf16 A-frags in K=16 slots 0..3 (upper half zero); packed RNE cvt
        short8 pa[2];
#pragma unroll
        for (int j = 0; j < 2; ++j) {
            float p0 = __builtin_amdgcn_exp2f(fmaf(S[j][0], LOG2E, -SHIFT_L2));
            float p1 = __builtin_amdgcn_exp2f(fmaf(S[j][1], LOG2E, -SHIFT_L2));
            float p2 = __builtin_amdgcn_exp2f(fmaf(S[j][2], LOG2E, -SHIFT_L2));
            float p3 = __builtin_amdgcn_exp2f(fmaf(S[j][3], LOG2E, -SHIFT_L2));
            lac[j] += (p0 + p1) + (p2 + p3);
            __hip_bfloat162 q01 = __float22bfloat162_rn(make_float2(p0, p1));
            __hip_bfloat162 q23 = __float22bfloat162_rn(make_float2(p2, p3));
            union { short8 s; unsigned int u[4]; } pk;
            __builtin_memcpy(&pk.u[0], &q01, 4);
            __builtin_memcpy(&pk.u[1], &q23, 4);
            pk.u[2] = 0; pk.u[3] = 0;
            pa[j] = pk.s;
        }

        // phase 2: U[batch][d] += P . M over k-slice [mblk*16, mblk*16+16)
        short8 bm[4];
#pragma unroll
        for (int dt = 0; dt < 4; ++dt) {
            short4v b4 = *(const short4v*)&Mt[(dt * 16 + lq) * STR + mblk * 16 + quad * 4];
            short8 b8;
#pragma unroll
            for (int e = 0; e < 4; ++e) { b8[e] = b4[e]; b8[e + 4] = 0; }
            bm[dt] = b8;
        }
#pragma unroll
        for (int j = 0; j < 2; ++j)
#pragma unroll
            for (int dt = 0; dt < 4; ++dt)
                Uacc[j][dt] = __builtin_amdgcn_mfma_f32_16x16x32_bf16(pa[j], bm[dt], Uacc[j][dt], 0, 0, 0);
    }

    // l reduction across quads (lane^16, lane^32 share a batch column)
    for (int j = 0; j < 2; ++j) {
        float v = lac[j];
        v += __shfl_xor(v, 16);
        v += __shfl_xor(v, 32);
        if (quad == 0) lsc[mblk][(nt0 + j) * 16 + lq] = v;
    }

    // U reduction across the 4 k-slice waves, in LDS (reuse buf0 as float [64][66])
    float* Ured = (float*)lds;
#pragma unroll
    for (int rnd = 0; rnd < 4; ++rnd) {
        __syncthreads();
        if (mblk == rnd) {
#pragma unroll
            for (int j = 0; j < 2; ++j)
#pragma unroll
                for (int dt = 0; dt < 4; ++dt)
#pragma unroll
                    for (int r4 = 0; r4 < 4; ++r4) {
                        int row = (nt0 + j) * 16 + quad * 4 + r4;
                        int col = dt * 16 + lq;
                        if (rnd == 0) Ured[row * 66 + col] = Uacc[j][dt][r4];
                        else          Ured[row * 66 + col] += Uacc[j][dt][r4];
                    }
        }
    }
    __syncthreads();

    // write partials
    float* pp = part + ((size_t)split * B_SZ + b0) * PSTRIDE;
    for (int i = t; i < 64 * D_SZ; i += 512) {
        int row = i / D_SZ, d = i - row * D_SZ;
        pp[(size_t)row * PSTRIDE + d] = Ured[row * 66 + d];
    }
    if (t < 64) {
        float Ls = lsc[0][t] + lsc[1][t] + lsc[2][t] + lsc[3][t];
        pp[(size_t)t * PSTRIDE + D_SZ] = Ls;
    }
}

// ---------------- fallback (round-2 kernel) for small ws ----------------
__global__ __launch_bounds__(512, 4)
void attend_partial_v2(const float* __restrict__ x, const float* __restrict__ M,
                       float* __restrict__ part, int slice) {
    __shared__ __align__(16) unsigned short lds[4 * 64 * STR];
    __shared__ float lsc[4][64];
    unsigned short* bufA  = lds;
    unsigned short* bufB  = lds + 64 * STR;
    unsigned short* Mc_hi = lds + 2 * 64 * STR;
    unsigned short* Mc_lo = lds + 3 * 64 * STR;

    const int t = threadIdx.x;
    const int w = t >> 6, lane = t & 63;
    const int quad = lane >> 4, lq = lane & 15;
    const int b0 = blockIdx.x * 64;
    const int split = blockIdx.y;
    const int kbeg = split * slice;
    const int kend = min(kbeg + slice, K_SZ);

    for (int i = t; i < 4 * 64 * STR; i += 512) lds[i] = 0;
    __syncthreads();
    for (int i = t; i < 64 * 25; i += 512) {
        int r = i / 25, cp = i - r * 25, c = cp * 2;
        float2 v = *(const float2*)&x[(size_t)(b0 + r) * D_SZ + c];
        unsigned short h0 = bf16_rne(v.x), h1 = bf16_rne(v.y);
        unsigned short l0 = bf16_rne(v.x - bf16_to_f(h0));
        unsigned short l1 = bf16_rne(v.y - bf16_to_f(h1));
        *(unsigned int*)&bufA[r * STR + c] = ((unsigned int)h1 << 16) | h0;
        *(unsigned int*)&bufB[r * STR + c] = ((unsigned int)l1 << 16) | l0;
    }
    __syncthreads();

    const int nt0 = (w & 1) * 2;
    const int mblk = w >> 1;
    short8 xh[2][2], xl[2][2];
    for (int j = 0; j < 2; ++j)
        for (int ki = 0; ki < 2; ++ki) {
            int off = ((nt0 + j) * 16 + lq) * STR + ki * 32 + quad * 8;
            xh[j][ki] = *(const short8*)&bufA[off];
            xl[j][ki] = *(const short8*)&bufB[off];
        }

    f32x4 Uacc[2] = {};
    float lac[2] = {0.f, 0.f};

    for (int k0 = kbeg; k0 < kend; k0 += CK) {
        __syncthreads();
        for (int i = t; i < 64 * 25; i += 512) {
            int r = i / 25, cp = i - r * 25, c = cp * 2;
            int kg = k0 + r;
            float2 v = make_float2(0.f, 0.f);
            if (kg < kend) v = *(const float2*)&M[(size_t)kg * D_SZ + c];
            unsigned short h0 = bf16_rne(v.x), h1 = bf16_rne(v.y);
            unsigned short l0 = bf16_rne(v.x - bf16_to_f(h0));
            unsigned short l1 = bf16_rne(v.y - bf16_to_f(h1));
            *(unsigned int*)&Mc_hi[r * STR + c] = ((unsigned int)h1 << 16) | h0;
            *(unsigned int*)&Mc_lo[r * STR + c] = ((unsigned int)l1 << 16) | l0;
            bufB[c * STR + r] = h0;
            bufB[(c + 1) * STR + r] = h1;
        }
        __syncthreads();

        f32x4 S[2] = {};
        for (int ki = 0; ki < 2; ++ki) {
            int aoff = (mblk * 16 + lq) * STR + ki * 32 + quad * 8;
            short8 ah = *(const short8*)&Mc_hi[aoff];
            short8 al = *(const short8*)&Mc_lo[aoff];
            for (int j = 0; j < 2; ++j) {
                S[j] = __builtin_amdgcn_mfma_f32_16x16x32_bf16(ah, xh[j][ki], S[j], 0, 0, 0);
                S[j] = __builtin_amdgcn_mfma_f32_16x16x32_bf16(ah, xl[j][ki], S[j], 0, 0, 0);
                S[j] = __builtin_amdgcn_mfma_f32_16x16x32_bf16(al, xh[j][ki], S[j], 0, 0, 0);
            }
        }
        for (int j = 0; j < 2; ++j) {
            unsigned short pb4[4];
#pragma unroll
            for (int r4 = 0; r4 < 4; ++r4) {
                float p = __expf(S[j][r4] - SHIFT);
                lac[j] += p;
                pb4[r4] = bf16_rne(p);
            }
            int b = (nt0 + j) * 16 + lq;
            int n0 = mblk * 16 + quad * 4;
            *(unsigned int*)&bufA[b * STR + n0]     = ((unsigned int)pb4[1] << 16) | pb4[0];
            *(unsigned int*)&bufA[b * STR + n0 + 2] = ((unsigned int)pb4[3] << 16) | pb4[2];
        }
        __syncthreads();
        for (int ki = 0; ki < 2; ++ki) {
            int poff = (mblk * 16 + lq) * STR + ki * 32 + quad * 8;
            short8 ap = *(const short8*)&bufA[poff];
            for (int j = 0; j < 2; ++j) {
                int doff = ((nt0 + j) * 16 + lq) * STR + ki * 32 + quad * 8;
                short8 bm = *(const short8*)&bufB[doff];
                Uacc[j] = __builtin_amdgcn_mfma_f32_16x16x32_bf16(ap, bm, Uacc[j], 0, 0, 0);
            }
        }
    }

    for (int j = 0; j < 2; ++j) {
        float v = lac[j];
        v += __shfl_xor(v, 16);
        v += __shfl_xor(v, 32);
        if (quad == 0) lsc[mblk][(nt0 + j) * 16 + lq] = v;
    }
    __syncthreads();
    float* pp = part + ((size_t)split * B_SZ + b0) * PSTRIDE;
    for (int j = 0; j < 2; ++j) {
        int d = (nt0 + j) * 16 + lq;
        if (d < D_SZ) {
#pragma unroll
            for (int r4 = 0; r4 < 4; ++r4) {
                int b = mblk * 16 + quad * 4 + r4;
                pp[(size_t)b * PSTRIDE + d] = Uacc[j][r4];
            }
        }
    }
    if (t < 64) {
        float Ls = lsc[0][t] + lsc[1][t] + lsc[2][t] + lsc[3][t];
        pp[(size_t)t * PSTRIDE + D_SZ] = Ls;
    }
}

__global__ __launch_bounds__(64)
void combine(const float* __restrict__ x, const float* __restrict__ part,
             float* __restrict__ out, int nsplit) {
    const int b = blockIdx.x;
    const int t = threadIdx.x;
    float L = 0.f;
    for (int s = 0; s < nsplit; ++s)
        L += part[((size_t)s * B_SZ + b) * PSTRIDE + D_SZ];
    if (t < D_SZ) {
        float acc = 0.f;
        for (int s = 0; s < nsplit; ++s)
            acc += part[((size_t)s * B_SZ + b) * PSTRIDE + t];
        out[(size_t)b * (2 * D_SZ) + t] = x[(size_t)b * D_SZ + t];
        out[(size_t)b * (2 * D_SZ) + D_SZ + t] = acc / L;
    }
}

extern "C" void kernel_launch(void* const* d_in, const int* in_sizes, int n_in,
                              void* d_out, int out_size, void* d_ws, size_t ws_size,
                              hipStream_t stream) {
    const float* x = (const float*)d_in[0];
    const float* M = (const float*)d_in[1];
    float* out = (float*)d_out;
    const size_t per_split = (size_t)B_SZ * PSTRIDE * sizeof(float);

    if (ws_size >= IMG_BYTES + 8 * per_split) {
        unsigned short* img = (unsigned short*)d_ws;
        float* part = (float*)((char*)d_ws + IMG_BYTES);
        int ns = (int)((ws_size - IMG_BYTES) / per_split);
        if (ns > 32) ns = 32;
        ns &= ~7;                                          // multiple of 8 for XCD swizzle
        int slice = (((K_SZ + ns - 1) / ns) + 63) & ~63;   // 64-aligned splits
        precompute_m<<<NCH, 256, 0, stream>>>(M, img);
        attend_fast<<<32 * ns, 512, 0, stream>>>(x, img, part, slice);
        combine<<<B_SZ, 64, 0, stream>>>(x, part, out, ns);
    } else {
        float* part = (float*)d_ws;
        int ns = (int)(ws_size / per_split);
        if (ns > 32) ns = 32;
        if (ns < 1) ns = 1;
        int slice = (K_SZ + ns - 1) / ns;
        dim3 gridA(B_SZ / 64, ns);
        attend_partial_v2<<<gridA, 512, 0, stream>>>(x, M, part, slice);
        combine<<<B_SZ, 64, 0, stream>>>(x, part, out, ns);
    }
}

// Round 13
// 194.083 us; speedup vs baseline: 3.2358x; 1.0251x over previous
//
#include <hip/hip_runtime.h>
#include <hip/hip_bf16.h>
#include <math.h>

#define B_SZ 2048
#define K_SZ 100000
#define D_SZ 50
#define BT   64       // batch rows per block (8 waves, 512 thr) — do NOT grow to 128/1024thr:
                      // r9 measured VGPR starvation (32 alloc vs ~60 need) -> 1.9GB scratch spill
#define CK   64
#define STR  72        // LDS/image row stride in 2B units; 144 B = 36 dwords (non-pow2)
#define SHIFT 30.0f    // bf16 P: fp32 exponent range, no subnormal cliff (f16 failed r4)
#define LOG2E 1.4426950408889634f
#define SHIFT_L2 43.280851226668905f   // SHIFT * LOG2E
#define PSTRIDE 52
#define NCH   1563     // ceil(100000/64)
#define IMG_CH 9216    // 2B units per chunk image: 2 * 64 * STR  ([Mhi bf16 | Mt bf16])
#define IMG_BYTES ((size_t)NCH * IMG_CH * 2)
#define NSEG  18       // 1024B segments per chunk image (18432 B)

typedef short short8 __attribute__((ext_vector_type(8)));
typedef short short4v __attribute__((ext_vector_type(4)));
typedef float f32x4 __attribute__((ext_vector_type(4)));

#if __has_builtin(__builtin_amdgcn_mfma_f32_16x16x16bf16_1k)
#define HAVE_BF16_K16 1
#else
#define HAVE_BF16_K16 0
#endif

__device__ __forceinline__ unsigned short bf16_rne(float f) {
    union { float f; unsigned int u; } v; v.f = f;
    unsigned int r = (v.u + 0x7fffu + ((v.u >> 16) & 1u)) >> 16;
    return (unsigned short)r;
}
__device__ __forceinline__ float bf16_to_f(unsigned short h) {
    union { unsigned int u; float f; } v; v.u = ((unsigned int)h) << 16;
    return v.f;
}

// async global->LDS, 16B per lane; LDS dest = wave-uniform base + lane*16 (m97/m104 semantics)
__device__ __forceinline__ void load_lds16(const void* g, void* l) {
    __builtin_amdgcn_global_load_lds(
        (const __attribute__((address_space(1))) unsigned int*)g,
        (__attribute__((address_space(3))) unsigned int*)l, 16, 0, 0);
}

// ---------------- prologue: M -> per-chunk image [Mhi bf16 | Mt bf16] ----------------
// r7 version VERBATIM (passed post-timing tripwires r7/r8/r11/r12).
// NO __threadfence: r11 measured it at +120us (per-block L2 writeback serialization).
__global__ __launch_bounds__(256)
void precompute_m(const float* __restrict__ M, unsigned short* __restrict__ img) {
    __shared__ __align__(16) unsigned short Mt[64 * STR];   // transpose scratch (9216)
    const int t = threadIdx.x;
    const int c0 = blockIdx.x;
    const int k0 = c0 * 64;
    for (int i = t; i < (64 * STR) / 2; i += 256) ((unsigned int*)Mt)[i] = 0;
    __syncthreads();
    unsigned int* gh = (unsigned int*)(img + (size_t)c0 * IMG_CH);   // 2304 dwords
    for (int i = t; i < 64 * 36; i += 256) {
        int r = i / 36, cd = i - r * 36, c = cd * 2;
        int kg = k0 + r;
        unsigned int val = 0;
        if (kg < K_SZ && c < D_SZ) {
            float2 v = *(const float2*)&M[(size_t)kg * D_SZ + c];
            val = ((unsigned int)bf16_rne(v.y) << 16) | bf16_rne(v.x);
            Mt[c * STR + r]       = (unsigned short)(val & 0xffffu);  // one-time transpose
            Mt[(c + 1) * STR + r] = (unsigned short)(val >> 16);
        }
        gh[i] = val;
    }
    __syncthreads();
    float4* go = (float4*)(img + (size_t)c0 * IMG_CH + 64 * STR);
    const float4* li = (const float4*)Mt;
    for (int i = t; i < (64 * STR) / 8; i += 256) go[i] = li[i];
}

// ---------------- hot kernel (r12 green + native K=16 bf16 phase-2) ----------------
// ph1: S[mem][batch] = Mhi . (xh + xl)^T  (2-pass x-side hi/lo split). exp in regs.
// ph2: exp(S) C-regs ARE the K=16 A-operand (C row=quad*4+r == A k=quad*4+j; identity
//      validated r4 via the f16 16x16x16 run, r5+ via the consistent-permutation emulation).
//      Native mfma_f32_16x16x16bf16_1k: no zero-padding, half the ph2 MFMA cycles.
// Staging: double-buffered global_load_lds dwordx4 + per-block chunk-order rotation.
__global__ __launch_bounds__(512, 4)
void attend_fast(const float* __restrict__ x, const unsigned short* __restrict__ img,
                 float* __restrict__ part, int slice) {
    __shared__ __align__(16) unsigned short lds[2 * IMG_CH];   // dbuf; buf0 reused as Ured
    __shared__ float lsc[4][64];

    const int t = threadIdx.x;
    const int w = t >> 6, lane = t & 63;
    const int quad = lane >> 4, lq = lane & 15;

    const int bid = blockIdx.x;
    const int rr = bid >> 3;
    const int split = (rr >> 5) * 8 + (bid & 7);   // same split -> same XCD (perf heuristic)
    const int xtile = rr & 31;
    const int b0 = xtile * BT;
    const int kbeg = split * slice;
    const int kend = min(kbeg + slice, K_SZ);

    const int nt0 = (w & 1) * 2;   // this wave's pair of batch 16-tiles
    const int mblk = w >> 1;       // this wave's memrow 16-tile (= its ph2 k-slice)

    // x fragments: direct global load + hi/lo bf16 split (K-loop invariant, cold path)
    short8 xh[2][2], xl[2][2];
    for (int j = 0; j < 2; ++j) {
        int row = b0 + (nt0 + j) * 16 + lq;
        const float* xr = x + (size_t)row * D_SZ;
        for (int ki = 0; ki < 2; ++ki) {
            int d0 = ki * 32 + quad * 8;
            float v[8];
#pragma unroll
            for (int e = 0; e < 8; ++e) v[e] = 0.f;
            if (d0 + 8 <= D_SZ) {
#pragma unroll
                for (int e = 0; e < 4; ++e) {
                    float2 f2 = *(const float2*)&xr[d0 + 2 * e];
                    v[2 * e] = f2.x; v[2 * e + 1] = f2.y;
                }
            } else if (d0 < D_SZ) {            // d0 == 48
                float2 f2 = *(const float2*)&xr[d0];
                v[0] = f2.x; v[1] = f2.y;
            }
            short8 sh, sl;
#pragma unroll
            for (int e = 0; e < 8; ++e) {
                unsigned short h = bf16_rne(v[e]);
                sh[e] = (short)h;
                sl[e] = (short)bf16_rne(v[e] - bf16_to_f(h));
            }
            xh[j][ki] = sh; xl[j][ki] = sl;
        }
    }

    f32x4 Uacc[2][4] = {};         // [batch tile j][d tile dt], partial over k-slice mblk
    float lac[2] = {0.f, 0.f};

    const int ci0 = kbeg >> 6;
    const int nch = (kend - kbeg + CK - 1) / CK;
    const int r0 = bid % nch;      // per-block rotation (de-phase co-resident blocks)

    // prologue DMA: rotated chunk r0 -> buf 0
    {
        const unsigned short* g = img + (size_t)(ci0 + r0) * IMG_CH;
        for (int seg = w; seg < NSEG; seg += 8)
            load_lds16((const unsigned int*)(g + seg * 512) + lane * 4, lds + seg * 512);
    }

    for (int i = 0; i < nch; ++i) {
        const int par = i & 1;
        unsigned short* cur = lds + par * IMG_CH;
        unsigned short* nxt = lds + (par ^ 1) * IMG_CH;

        __builtin_amdgcn_s_waitcnt(0);   // explicit full drain (vm+lgkm) — DMA hardening
        __syncthreads();   // drains DMA of chunk i (in flight during iter i-1's compute);
                           // fences iter i-1's reads of `nxt` before we overwrite it

        if (i + 1 < nch) { // prefetch rotated chunk i+1 (overlaps with this iter's compute)
            int cc = r0 + i + 1; if (cc >= nch) cc -= nch;
            const unsigned short* g = img + (size_t)(ci0 + cc) * IMG_CH;
            for (int seg = w; seg < NSEG; seg += 8)
                load_lds16((const unsigned int*)(g + seg * 512) + lane * 4, nxt + seg * 512);
        }

        const unsigned short* Mhi = cur;
        const unsigned short* Mt  = cur + 64 * STR;

        // phase 1: S[m=memrow][n=batch], 2-pass (x-side hi/lo)
        f32x4 S[2] = {};
#pragma unroll
        for (int ki = 0; ki < 2; ++ki) {
            int aoff = (mblk * 16 + lq) * STR + ki * 32 + quad * 8;
            short8 ah = *(const short8*)&Mhi[aoff];
#pragma unroll
            for (int j = 0; j < 2; ++j) {
                S[j] = __builtin_amdgcn_mfma_f32_16x16x32_bf16(ah, xh[j][ki], S[j], 0, 0, 0);
                S[j] = __builtin_amdgcn_mfma_f32_16x16x32_bf16(ah, xl[j][ki], S[j], 0, 0, 0);
            }
        }

#if HAVE_BF16_K16
        // exp -> bf16 A-frags (4 elems, native K=16); packed RNE cvt
        short4v pa[2];
#pragma unroll
        for (int j = 0; j < 2; ++j) {
            float p0 = __builtin_amdgcn_exp2f(fmaf(S[j][0], LOG2E, -SHIFT_L2));
            float p1 = __builtin_amdgcn_exp2f(fmaf(S[j][1], LOG2E, -SHIFT_L2));
            float p2 = __builtin_amdgcn_exp2f(fmaf(S[j][2], LOG2E, -SHIFT_L2));
            float p3 = __builtin_amdgcn_exp2f(fmaf(S[j][3], LOG2E, -SHIFT_L2));
            lac[j] += (p0 + p1) + (p2 + p3);
            __hip_bfloat162 q01 = __float22bfloat162_rn(make_float2(p0, p1));
            __hip_bfloat162 q23 = __float22bfloat162_rn(make_float2(p2, p3));
            union { short4v s; unsigned int u[2]; } pk;
            __builtin_memcpy(&pk.u[0], &q01, 4);
            __builtin_memcpy(&pk.u[1], &q23, 4);
            pa[j] = pk.s;
        }

        // phase 2: U[batch][d] += P . M over k-slice [mblk*16, mblk*16+16), native K=16
#pragma unroll
        for (int dt = 0; dt < 4; ++dt) {
            short4v bm = *(const short4v*)&Mt[(dt * 16 + lq) * STR + mblk * 16 + quad * 4];
#pragma unroll
            for (int j = 0; j < 2; ++j)
                Uacc[j][dt] = __builtin_amdgcn_mfma_f32_16x16x16bf16_1k(pa[j], bm, Uacc[j][dt], 0, 0, 0);
        }
#else
        // fallback: r12 emulation (K=16 in lower half of a K=32 MFMA, upper half zero)
        short8 pa[2];
#pragma unroll
        for (int j = 0; j < 2; ++j) {
            float p0 = __builtin_amdgcn_exp2f(fmaf(S[j][0], LOG2E, -SHIFT_L2));
            float p1 = __builtin_amdgcn_exp2f(fmaf(S[j][1], LOG2E, -SHIFT_L2));
            float p2 = __builtin_amdgcn_exp2f(fmaf(S[j][2], LOG2E, -SHIFT_L2));
            float p3 = __builtin_amdgcn_exp2f(fmaf(S[j][3], LOG2E, -SHIFT_L2));
            lac[j] += (p0 + p1) + (p2 + p3);
            __hip_bfloat162 q01 = __float22bfloat162_rn(make_float2(p0, p1));
            __hip_bfloat162 q23 = __float22bfloat162_rn(make_float2(p2, p3));
            union { short8 s; unsigned int u[4]; } pk;
            __builtin_memcpy(&pk.u[0], &q01, 4);
            __builtin_memcpy(&pk.u[1], &q23, 4);
            pk.u[2] = 0; pk.u[3] = 0;
            pa[j] = pk.s;
        }
#pragma unroll
        for (int dt = 0; dt < 4; ++dt) {
            short4v b4 = *(const short4v*)&Mt[(dt * 16 + lq) * STR + mblk * 16 + quad * 4];
            short8 b8;
#pragma unroll
            for (int e = 0; e < 4; ++e) { b8[e] = b4[e]; b8[e + 4] = 0; }
#pragma unroll
            for (int j = 0; j < 2; ++j)
                Uacc[j][dt] = __builtin_amdgcn_mfma_f32_16x16x32_bf16(pa[j], b8, Uacc[j][dt], 0, 0, 0);
        }
#endif
    }

    // l reduction across quads (lane^16, lane^32 share a batch column)
    for (int j = 0; j < 2; ++j) {
        float v = lac[j];
        v += __shfl_xor(v, 16);
        v += __shfl_xor(v, 32);
        if (quad == 0) lsc[mblk][(nt0 + j) * 16 + lq] = v;
    }

    // U reduction across the 4 k-slice waves, in LDS (reuse buf0 as float [64][66])
    float* Ured = (float*)lds;
#pragma unroll
    for (int rnd = 0; rnd < 4; ++rnd) {
        __syncthreads();
        if (mblk == rnd) {
#pragma unroll
            for (int j = 0; j < 2; ++j)
#pragma unroll
                for (int dt = 0; dt < 4; ++dt)
#pragma unroll
                    for (int r4 = 0; r4 < 4; ++r4) {
                        int row = (nt0 + j) * 16 + quad * 4 + r4;
                        int col = dt * 16 + lq;
                        if (rnd == 0) Ured[row * 66 + col] = Uacc[j][dt][r4];
                        else          Ured[row * 66 + col] += Uacc[j][dt][r4];
                    }
        }
    }
    __syncthreads();

    // write partials
    float* pp = part + ((size_t)split * B_SZ + b0) * PSTRIDE;
    for (int i = t; i < 64 * D_SZ; i += 512) {
        int row = i / D_SZ, d = i - row * D_SZ;
        pp[(size_t)row * PSTRIDE + d] = Ured[row * 66 + d];
    }
    if (t < 64) {
        float Ls = lsc[0][t] + lsc[1][t] + lsc[2][t] + lsc[3][t];
        pp[(size_t)t * PSTRIDE + D_SZ] = Ls;
    }
}

// ---------------- fallback (round-2 kernel) for small ws ----------------
__global__ __launch_bounds__(512, 4)
void attend_partial_v2(const float* __restrict__ x, const float* __restrict__ M,
                       float* __restrict__ part, int slice) {
    __shared__ __align__(16) unsigned short lds[4 * 64 * STR];
    __shared__ float lsc[4][64];
    unsigned short* bufA  = lds;
    unsigned short* bufB  = lds + 64 * STR;
    unsigned short* Mc_hi = lds + 2 * 64 * STR;
    unsigned short* Mc_lo = lds + 3 * 64 * STR;

    const int t = threadIdx.x;
    const int w = t >> 6, lane = t & 63;
    const int quad = lane >> 4, lq = lane & 15;
    const int b0 = blockIdx.x * 64;
    const int split = blockIdx.y;
    const int kbeg = split * slice;
    const int kend = min(kbeg + slice, K_SZ);

    for (int i = t; i < 4 * 64 * STR; i += 512) lds[i] = 0;
    __syncthreads();
    for (int i = t; i < 64 * 25; i += 512) {
        int r = i / 25, cp = i - r * 25, c = cp * 2;
        float2 v = *(const float2*)&x[(size_t)(b0 + r) * D_SZ + c];
        unsigned short h0 = bf16_rne(v.x), h1 = bf16_rne(v.y);
        unsigned short l0 = bf16_rne(v.x - bf16_to_f(h0));
        unsigned short l1 = bf16_rne(v.y - bf16_to_f(h1));
        *(unsigned int*)&bufA[r * STR + c] = ((unsigned int)h1 << 16) | h0;
        *(unsigned int*)&bufB[r * STR + c] = ((unsigned int)l1 << 16) | l0;
    }
    __syncthreads();

    const int nt0 = (w & 1) * 2;
    const int mblk = w >> 1;
    short8 xh[2][2], xl[2][2];
    for (int j = 0; j < 2; ++j)
        for (int ki = 0; ki < 2; ++ki) {
            int off = ((nt0 + j) * 16 + lq) * STR + ki * 32 + quad * 8;
            xh[j][ki] = *(const short8*)&bufA[off];
            xl[j][ki] = *(const short8*)&bufB[off];
        }

    f32x4 Uacc[2] = {};
    float lac[2] = {0.f, 0.f};

    for (int k0 = kbeg; k0 < kend; k0 += CK) {
        __syncthreads();
        for (int i = t; i < 64 * 25; i += 512) {
            int r = i / 25, cp = i - r * 25, c = cp * 2;
            int kg = k0 + r;
            float2 v = make_float2(0.f, 0.f);
            if (kg < kend) v = *(const float2*)&M[(size_t)kg * D_SZ + c];
            unsigned short h0 = bf16_rne(v.x), h1 = bf16_rne(v.y);
            unsigned short l0 = bf16_rne(v.x - bf16_to_f(h0));
            unsigned short l1 = bf16_rne(v.y - bf16_to_f(h1));
            *(unsigned int*)&Mc_hi[r * STR + c] = ((unsigned int)h1 << 16) | h0;
            *(unsigned int*)&Mc_lo[r * STR + c] = ((unsigned int)l1 << 16) | l0;
            bufB[c * STR + r] = h0;
            bufB[(c + 1) * STR + r] = h1;
        }
        __syncthreads();

        f32x4 S[2] = {};
        for (int ki = 0; ki < 2; ++ki) {
            int aoff = (mblk * 16 + lq) * STR + ki * 32 + quad * 8;
            short8 ah = *(const short8*)&Mc_hi[aoff];
            short8 al = *(const short8*)&Mc_lo[aoff];
            for (int j = 0; j < 2; ++j) {
                S[j] = __builtin_amdgcn_mfma_f32_16x16x32_bf16(ah, xh[j][ki], S[j], 0, 0, 0);
                S[j] = __builtin_amdgcn_mfma_f32_16x16x32_bf16(ah, xl[j][ki], S[j], 0, 0, 0);
                S[j] = __builtin_amdgcn_mfma_f32_16x16x32_bf16(al, xh[j][ki], S[j], 0, 0, 0);
            }
        }
        for (int j = 0; j < 2; ++j) {
            unsigned short pb4[4];
#pragma unroll
            for (int r4 = 0; r4 < 4; ++r4) {
                float p = __expf(S[j][r4] - SHIFT);
                lac[j] += p;
                pb4[r4] = bf16_rne(p);
            }
            int b = (nt0 + j) * 16 + lq;
            int n0 = mblk * 16 + quad * 4;
            *(unsigned int*)&bufA[b * STR + n0]     = ((unsigned int)pb4[1] << 16) | pb4[0];
            *(unsigned int*)&bufA[b * STR + n0 + 2] = ((unsigned int)pb4[3] << 16) | pb4[2];
        }
        __syncthreads();
        for (int ki = 0; ki < 2; ++ki) {
            int poff = (mblk * 16 + lq) * STR + ki * 32 + quad * 8;
            short8 ap = *(const short8*)&bufA[poff];
            for (int j = 0; j < 2; ++j) {
                int doff = ((nt0 + j) * 16 + lq) * STR + ki * 32 + quad * 8;
                short8 bm = *(const short8*)&bufB[doff];
                Uacc[j] = __builtin_amdgcn_mfma_f32_16x16x32_bf16(ap, bm, Uacc[j], 0, 0, 0);
            }
        }
    }

    for (int j = 0; j < 2; ++j) {
        float v = lac[j];
        v += __shfl_xor(v, 16);
        v += __shfl_xor(v, 32);
        if (quad == 0) lsc[mblk][(nt0 + j) * 16 + lq] = v;
    }
    __syncthreads();
    float* pp = part + ((size_t)split * B_SZ + b0) * PSTRIDE;
    for (int j = 0; j < 2; ++j) {
        int d = (nt0 + j) * 16 + lq;
        if (d < D_SZ) {
#pragma unroll
            for (int r4 = 0; r4 < 4; ++r4) {
                int b = mblk * 16 + quad * 4 + r4;
                pp[(size_t)b * PSTRIDE + d] = Uacc[j][r4];
            }
        }
    }
    if (t < 64) {
        float Ls = lsc[0][t] + lsc[1][t] + lsc[2][t] + lsc[3][t];
        pp[(size_t)t * PSTRIDE + D_SZ] = Ls;
    }
}

__global__ __launch_bounds__(64)
void combine(const float* __restrict__ x, const float* __restrict__ part,
             float* __restrict__ out, int nsplit) {
    const int b = blockIdx.x;
    const int t = threadIdx.x;
    float L = 0.f;
    for (int s = 0; s < nsplit; ++s)
        L += part[((size_t)s * B_SZ + b) * PSTRIDE + D_SZ];
    if (t < D_SZ) {
        float acc = 0.f;
        for (int s = 0; s < nsplit; ++s)
            acc += part[((size_t)s * B_SZ + b) * PSTRIDE + t];
        out[(size_t)b * (2 * D_SZ) + t] = x[(size_t)b * D_SZ + t];
        out[(size_t)b * (2 * D_SZ) + D_SZ + t] = acc / L;
    }
}

extern "C" void kernel_launch(void* const* d_in, const int* in_sizes, int n_in,
                              void* d_out, int out_size, void* d_ws, size_t ws_size,
                              hipStream_t stream) {
    const float* x = (const float*)d_in[0];
    const float* M = (const float*)d_in[1];
    float* out = (float*)d_out;
    const size_t per_split = (size_t)B_SZ * PSTRIDE * sizeof(float);

    if (ws_size >= IMG_BYTES + 8 * per_split) {
        unsigned short* img = (unsigned short*)d_ws;
        float* part = (float*)((char*)d_ws + IMG_BYTES);
        int ns = (int)((ws_size - IMG_BYTES) / per_split);
        if (ns > 32) ns = 32;
        ns &= ~7;                                          // multiple of 8 for XCD swizzle
        int slice = (((K_SZ + ns - 1) / ns) + 63) & ~63;   // 64-aligned splits
        precompute_m<<<NCH, 256, 0, stream>>>(M, img);
        attend_fast<<<32 * ns, 512, 0, stream>>>(x, img, part, slice);
        combine<<<B_SZ, 64, 0, stream>>>(x, part, out, ns);
    } else {
        float* part = (float*)d_ws;
        int ns = (int)(ws_size / per_split);
        if (ns > 32) ns = 32;
        if (ns < 1) ns = 1;
        int slice = (K_SZ + ns - 1) / ns;
        dim3 gridA(B_SZ / 64, ns);
        attend_partial_v2<<<gridA, 512, 0, stream>>>(x, M, part, slice);
        combine<<<B_SZ, 64, 0, stream>>>(x, part, out, ns);
    }
}

// Round 14
// 191.810 us; speedup vs baseline: 3.2741x; 1.0118x over previous
//
#include <hip/hip_runtime.h>
#include <hip/hip_bf16.h>
#include <math.h>

#define B_SZ 2048
#define K_SZ 100000
#define D_SZ 50
#define BT   64       // batch rows per block (8 waves, 512 thr) — do NOT grow to 128/1024thr:
                      // r9 measured VGPR starvation (32 alloc vs ~60 need) -> 1.9GB scratch spill
#define CK   64
#define STR  72        // LDS/image row stride in 2B units; 144 B = 36 dwords (non-pow2)
#define MTS  78        // precompute Mt scratch stride (39 dwords, odd -> scatter ~2-way not 8-way)
#define SHIFT 30.0f    // bf16 P: fp32 exponent range, no subnormal cliff (f16 failed r4)
#define LOG2E 1.4426950408889634f
#define SHIFT_L2 43.280851226668905f   // SHIFT * LOG2E
#define PSTRIDE 52
#define NCH   1563     // ceil(100000/64)
#define IMG_CH 9216    // 2B units per chunk image: 2 * 64 * STR  ([Mhi bf16 | Mt bf16])
#define IMG_BYTES ((size_t)NCH * IMG_CH * 2)
#define NSEG  18       // 1024B segments per chunk image (18432 B)

typedef short short8 __attribute__((ext_vector_type(8)));
typedef short short4v __attribute__((ext_vector_type(4)));
typedef float f32x4 __attribute__((ext_vector_type(4)));

#if __has_builtin(__builtin_amdgcn_mfma_f32_16x16x16bf16_1k)
#define HAVE_BF16_K16 1
#else
#define HAVE_BF16_K16 0
#endif

__device__ __forceinline__ unsigned short bf16_rne(float f) {
    union { float f; unsigned int u; } v; v.f = f;
    unsigned int r = (v.u + 0x7fffu + ((v.u >> 16) & 1u)) >> 16;
    return (unsigned short)r;
}
__device__ __forceinline__ float bf16_to_f(unsigned short h) {
    union { unsigned int u; float f; } v; v.u = ((unsigned int)h) << 16;
    return v.f;
}

// async global->LDS, 16B per lane; LDS dest = wave-uniform base + lane*16 (m97/m104 semantics)
__device__ __forceinline__ void load_lds16(const void* g, void* l) {
    __builtin_amdgcn_global_load_lds(
        (const __attribute__((address_space(1))) unsigned int*)g,
        (__attribute__((address_space(3))) unsigned int*)l, 16, 0, 0);
}

// ---------------- prologue: M -> per-chunk image [Mhi bf16 | Mt bf16] ----------------
// r7 structure (two barriers, zero-init, LDS transpose scratch, bulk copy-out) with the
// scatter de-conflicted: scratch stride 78 u16 (odd dword stride -> all 32 banks, ~2-way
// vs r7's 8-way) and dword-wise conflict-free copy-out.
// NO __threadfence: r11 measured it at +120us (per-block L2 writeback serialization).
__global__ __launch_bounds__(256)
void precompute_m(const float* __restrict__ M, unsigned short* __restrict__ img) {
    __shared__ __align__(16) unsigned short Mt[64 * MTS];   // transpose scratch (9984 B)
    const int t = threadIdx.x;
    const int c0 = blockIdx.x;
    const int k0 = c0 * 64;
    for (int i = t; i < (64 * MTS) / 2; i += 256) ((unsigned int*)Mt)[i] = 0;
    __syncthreads();
    unsigned int* gh = (unsigned int*)(img + (size_t)c0 * IMG_CH);   // 2304 dwords
    for (int i = t; i < 64 * 36; i += 256) {
        int r = i / 36, cd = i - r * 36, c = cd * 2;
        int kg = k0 + r;
        unsigned int val = 0;
        if (kg < K_SZ && c < D_SZ) {
            float2 v = *(const float2*)&M[(size_t)kg * D_SZ + c];
            val = ((unsigned int)bf16_rne(v.y) << 16) | bf16_rne(v.x);
            Mt[c * MTS + r]       = (unsigned short)(val & 0xffffu);  // one-time transpose
            Mt[(c + 1) * MTS + r] = (unsigned short)(val >> 16);
        }
        gh[i] = val;
    }
    __syncthreads();
    // copy-out: image d-row r, dwords c=0..35 (u16 pairs 2c,2c+1; cols >=64 are zero pad)
    unsigned int* gt = (unsigned int*)(img + (size_t)c0 * IMG_CH + 64 * STR);
    for (int i = t; i < 64 * 36; i += 256) {
        int r = i / 36, c = i - r * 36;
        gt[i] = *(const unsigned int*)&Mt[r * MTS + c * 2];   // dword-aligned (MTS even)
    }
}

// ---------------- hot kernel (r13 green, byte-identical) ----------------
// ph1: S[mem][batch] = Mhi . (xh + xl)^T  (2-pass x-side hi/lo split). exp in regs.
// ph2: exp(S) C-regs ARE the K=16 A-operand; native mfma_f32_16x16x16bf16_1k.
// Staging: double-buffered global_load_lds dwordx4 + per-block chunk-order rotation.
__global__ __launch_bounds__(512, 4)
void attend_fast(const float* __restrict__ x, const unsigned short* __restrict__ img,
                 float* __restrict__ part, int slice) {
    __shared__ __align__(16) unsigned short lds[2 * IMG_CH];   // dbuf; buf0 reused as Ured
    __shared__ float lsc[4][64];

    const int t = threadIdx.x;
    const int w = t >> 6, lane = t & 63;
    const int quad = lane >> 4, lq = lane & 15;

    const int bid = blockIdx.x;
    const int rr = bid >> 3;
    const int split = (rr >> 5) * 8 + (bid & 7);   // same split -> same XCD (perf heuristic)
    const int xtile = rr & 31;
    const int b0 = xtile * BT;
    const int kbeg = split * slice;
    const int kend = min(kbeg + slice, K_SZ);

    const int nt0 = (w & 1) * 2;   // this wave's pair of batch 16-tiles
    const int mblk = w >> 1;       // this wave's memrow 16-tile (= its ph2 k-slice)

    // x fragments: direct global load + hi/lo bf16 split (K-loop invariant, cold path)
    short8 xh[2][2], xl[2][2];
    for (int j = 0; j < 2; ++j) {
        int row = b0 + (nt0 + j) * 16 + lq;
        const float* xr = x + (size_t)row * D_SZ;
        for (int ki = 0; ki < 2; ++ki) {
            int d0 = ki * 32 + quad * 8;
            float v[8];
#pragma unroll
            for (int e = 0; e < 8; ++e) v[e] = 0.f;
            if (d0 + 8 <= D_SZ) {
#pragma unroll
                for (int e = 0; e < 4; ++e) {
                    float2 f2 = *(const float2*)&xr[d0 + 2 * e];
                    v[2 * e] = f2.x; v[2 * e + 1] = f2.y;
                }
            } else if (d0 < D_SZ) {            // d0 == 48
                float2 f2 = *(const float2*)&xr[d0];
                v[0] = f2.x; v[1] = f2.y;
            }
            short8 sh, sl;
#pragma unroll
            for (int e = 0; e < 8; ++e) {
                unsigned short h = bf16_rne(v[e]);
                sh[e] = (short)h;
                sl[e] = (short)bf16_rne(v[e] - bf16_to_f(h));
            }
            xh[j][ki] = sh; xl[j][ki] = sl;
        }
    }

    f32x4 Uacc[2][4] = {};         // [batch tile j][d tile dt], partial over k-slice mblk
    float lac[2] = {0.f, 0.f};

    const int ci0 = kbeg >> 6;
    const int nch = (kend - kbeg + CK - 1) / CK;
    const int r0 = bid % nch;      // per-block rotation (de-phase co-resident blocks)

    // prologue DMA: rotated chunk r0 -> buf 0
    {
        const unsigned short* g = img + (size_t)(ci0 + r0) * IMG_CH;
        for (int seg = w; seg < NSEG; seg += 8)
            load_lds16((const unsigned int*)(g + seg * 512) + lane * 4, lds + seg * 512);
    }

    for (int i = 0; i < nch; ++i) {
        const int par = i & 1;
        unsigned short* cur = lds + par * IMG_CH;
        unsigned short* nxt = lds + (par ^ 1) * IMG_CH;

        __builtin_amdgcn_s_waitcnt(0);   // explicit full drain (vm+lgkm) — DMA hardening
        __syncthreads();   // drains DMA of chunk i (in flight during iter i-1's compute);
                           // fences iter i-1's reads of `nxt` before we overwrite it

        if (i + 1 < nch) { // prefetch rotated chunk i+1 (overlaps with this iter's compute)
            int cc = r0 + i + 1; if (cc >= nch) cc -= nch;
            const unsigned short* g = img + (size_t)(ci0 + cc) * IMG_CH;
            for (int seg = w; seg < NSEG; seg += 8)
                load_lds16((const unsigned int*)(g + seg * 512) + lane * 4, nxt + seg * 512);
        }

        const unsigned short* Mhi = cur;
        const unsigned short* Mt  = cur + 64 * STR;

        // phase 1: S[m=memrow][n=batch], 2-pass (x-side hi/lo)
        f32x4 S[2] = {};
#pragma unroll
        for (int ki = 0; ki < 2; ++ki) {
            int aoff = (mblk * 16 + lq) * STR + ki * 32 + quad * 8;
            short8 ah = *(const short8*)&Mhi[aoff];
#pragma unroll
            for (int j = 0; j < 2; ++j) {
                S[j] = __builtin_amdgcn_mfma_f32_16x16x32_bf16(ah, xh[j][ki], S[j], 0, 0, 0);
                S[j] = __builtin_amdgcn_mfma_f32_16x16x32_bf16(ah, xl[j][ki], S[j], 0, 0, 0);
            }
        }

#if HAVE_BF16_K16
        // exp -> bf16 A-frags (4 elems, native K=16); packed RNE cvt
        short4v pa[2];
#pragma unroll
        for (int j = 0; j < 2; ++j) {
            float p0 = __builtin_amdgcn_exp2f(fmaf(S[j][0], LOG2E, -SHIFT_L2));
            float p1 = __builtin_amdgcn_exp2f(fmaf(S[j][1], LOG2E, -SHIFT_L2));
            float p2 = __builtin_amdgcn_exp2f(fmaf(S[j][2], LOG2E, -SHIFT_L2));
            float p3 = __builtin_amdgcn_exp2f(fmaf(S[j][3], LOG2E, -SHIFT_L2));
            lac[j] += (p0 + p1) + (p2 + p3);
            __hip_bfloat162 q01 = __float22bfloat162_rn(make_float2(p0, p1));
            __hip_bfloat162 q23 = __float22bfloat162_rn(make_float2(p2, p3));
            union { short4v s; unsigned int u[2]; } pk;
            __builtin_memcpy(&pk.u[0], &q01, 4);
            __builtin_memcpy(&pk.u[1], &q23, 4);
            pa[j] = pk.s;
        }

        // phase 2: U[batch][d] += P . M over k-slice [mblk*16, mblk*16+16), native K=16
#pragma unroll
        for (int dt = 0; dt < 4; ++dt) {
            short4v bm = *(const short4v*)&Mt[(dt * 16 + lq) * STR + mblk * 16 + quad * 4];
#pragma unroll
            for (int j = 0; j < 2; ++j)
                Uacc[j][dt] = __builtin_amdgcn_mfma_f32_16x16x16bf16_1k(pa[j], bm, Uacc[j][dt], 0, 0, 0);
        }
#else
        // fallback: r12 emulation (K=16 in lower half of a K=32 MFMA, upper half zero)
        short8 pa[2];
#pragma unroll
        for (int j = 0; j < 2; ++j) {
            float p0 = __builtin_amdgcn_exp2f(fmaf(S[j][0], LOG2E, -SHIFT_L2));
            float p1 = __builtin_amdgcn_exp2f(fmaf(S[j][1], LOG2E, -SHIFT_L2));
            float p2 = __builtin_amdgcn_exp2f(fmaf(S[j][2], LOG2E, -SHIFT_L2));
            float p3 = __builtin_amdgcn_exp2f(fmaf(S[j][3], LOG2E, -SHIFT_L2));
            lac[j] += (p0 + p1) + (p2 + p3);
            __hip_bfloat162 q01 = __float22bfloat162_rn(make_float2(p0, p1));
            __hip_bfloat162 q23 = __float22bfloat162_rn(make_float2(p2, p3));
            union { short8 s; unsigned int u[4]; } pk;
            __builtin_memcpy(&pk.u[0], &q01, 4);
            __builtin_memcpy(&pk.u[1], &q23, 4);
            pk.u[2] = 0; pk.u[3] = 0;
            pa[j] = pk.s;
        }
#pragma unroll
        for (int dt = 0; dt < 4; ++dt) {
            short4v b4 = *(const short4v*)&Mt[(dt * 16 + lq) * STR + mblk * 16 + quad * 4];
            short8 b8;
#pragma unroll
            for (int e = 0; e < 4; ++e) { b8[e] = b4[e]; b8[e + 4] = 0; }
#pragma unroll
            for (int j = 0; j < 2; ++j)
                Uacc[j][dt] = __builtin_amdgcn_mfma_f32_16x16x32_bf16(pa[j], b8, Uacc[j][dt], 0, 0, 0);
        }
#endif
    }

    // l reduction across quads (lane^16, lane^32 share a batch column)
    for (int j = 0; j < 2; ++j) {
        float v = lac[j];
        v += __shfl_xor(v, 16);
        v += __shfl_xor(v, 32);
        if (quad == 0) lsc[mblk][(nt0 + j) * 16 + lq] = v;
    }

    // U reduction across the 4 k-slice waves, in LDS (reuse buf0 as float [64][66])
    float* Ured = (float*)lds;
#pragma unroll
    for (int rnd = 0; rnd < 4; ++rnd) {
        __syncthreads();
        if (mblk == rnd) {
#pragma unroll
            for (int j = 0; j < 2; ++j)
#pragma unroll
                for (int dt = 0; dt < 4; ++dt)
#pragma unroll
                    for (int r4 = 0; r4 < 4; ++r4) {
                        int row = (nt0 + j) * 16 + quad * 4 + r4;
                        int col = dt * 16 + lq;
                        if (rnd == 0) Ured[row * 66 + col] = Uacc[j][dt][r4];
                        else          Ured[row * 66 + col] += Uacc[j][dt][r4];
                    }
        }
    }
    __syncthreads();

    // write partials
    float* pp = part + ((size_t)split * B_SZ + b0) * PSTRIDE;
    for (int i = t; i < 64 * D_SZ; i += 512) {
        int row = i / D_SZ, d = i - row * D_SZ;
        pp[(size_t)row * PSTRIDE + d] = Ured[row * 66 + d];
    }
    if (t < 64) {
        float Ls = lsc[0][t] + lsc[1][t] + lsc[2][t] + lsc[3][t];
        pp[(size_t)t * PSTRIDE + D_SZ] = Ls;
    }
}

// ---------------- fallback (round-2 kernel) for small ws ----------------
__global__ __launch_bounds__(512, 4)
void attend_partial_v2(const float* __restrict__ x, const float* __restrict__ M,
                       float* __restrict__ part, int slice) {
    __shared__ __align__(16) unsigned short lds[4 * 64 * STR];
    __shared__ float lsc[4][64];
    unsigned short* bufA  = lds;
    unsigned short* bufB  = lds + 64 * STR;
    unsigned short* Mc_hi = lds + 2 * 64 * STR;
    unsigned short* Mc_lo = lds + 3 * 64 * STR;

    const int t = threadIdx.x;
    const int w = t >> 6, lane = t & 63;
    const int quad = lane >> 4, lq = lane & 15;
    const int b0 = blockIdx.x * 64;
    const int split = blockIdx.y;
    const int kbeg = split * slice;
    const int kend = min(kbeg + slice, K_SZ);

    for (int i = t; i < 4 * 64 * STR; i += 512) lds[i] = 0;
    __syncthreads();
    for (int i = t; i < 64 * 25; i += 512) {
        int r = i / 25, cp = i - r * 25, c = cp * 2;
        float2 v = *(const float2*)&x[(size_t)(b0 + r) * D_SZ + c];
        unsigned short h0 = bf16_rne(v.x), h1 = bf16_rne(v.y);
        unsigned short l0 = bf16_rne(v.x - bf16_to_f(h0));
        unsigned short l1 = bf16_rne(v.y - bf16_to_f(h1));
        *(unsigned int*)&bufA[r * STR + c] = ((unsigned int)h1 << 16) | h0;
        *(unsigned int*)&bufB[r * STR + c] = ((unsigned int)l1 << 16) | l0;
    }
    __syncthreads();

    const int nt0 = (w & 1) * 2;
    const int mblk = w >> 1;
    short8 xh[2][2], xl[2][2];
    for (int j = 0; j < 2; ++j)
        for (int ki = 0; ki < 2; ++ki) {
            int off = ((nt0 + j) * 16 + lq) * STR + ki * 32 + quad * 8;
            xh[j][ki] = *(const short8*)&bufA[off];
            xl[j][ki] = *(const short8*)&bufB[off];
        }

    f32x4 Uacc[2] = {};
    float lac[2] = {0.f, 0.f};

    for (int k0 = kbeg; k0 < kend; k0 += CK) {
        __syncthreads();
        for (int i = t; i < 64 * 25; i += 512) {
            int r = i / 25, cp = i - r * 25, c = cp * 2;
            int kg = k0 + r;
            float2 v = make_float2(0.f, 0.f);
            if (kg < kend) v = *(const float2*)&M[(size_t)kg * D_SZ + c];
            unsigned short h0 = bf16_rne(v.x), h1 = bf16_rne(v.y);
            unsigned short l0 = bf16_rne(v.x - bf16_to_f(h0));
            unsigned short l1 = bf16_rne(v.y - bf16_to_f(h1));
            *(unsigned int*)&Mc_hi[r * STR + c] = ((unsigned int)h1 << 16) | h0;
            *(unsigned int*)&Mc_lo[r * STR + c] = ((unsigned int)l1 << 16) | l0;
            bufB[c * STR + r] = h0;
            bufB[(c + 1) * STR + r] = h1;
        }
        __syncthreads();

        f32x4 S[2] = {};
        for (int ki = 0; ki < 2; ++ki) {
            int aoff = (mblk * 16 + lq) * STR + ki * 32 + quad * 8;
            short8 ah = *(const short8*)&Mc_hi[aoff];
            short8 al = *(const short8*)&Mc_lo[aoff];
            for (int j = 0; j < 2; ++j) {
                S[j] = __builtin_amdgcn_mfma_f32_16x16x32_bf16(ah, xh[j][ki], S[j], 0, 0, 0);
                S[j] = __builtin_amdgcn_mfma_f32_16x16x32_bf16(ah, xl[j][ki], S[j], 0, 0, 0);
                S[j] = __builtin_amdgcn_mfma_f32_16x16x32_bf16(al, xh[j][ki], S[j], 0, 0, 0);
            }
        }
        for (int j = 0; j < 2; ++j) {
            unsigned short pb4[4];
#pragma unroll
            for (int r4 = 0; r4 < 4; ++r4) {
                float p = __expf(S[j][r4] - SHIFT);
                lac[j] += p;
                pb4[r4] = bf16_rne(p);
            }
            int b = (nt0 + j) * 16 + lq;
            int n0 = mblk * 16 + quad * 4;
            *(unsigned int*)&bufA[b * STR + n0]     = ((unsigned int)pb4[1] << 16) | pb4[0];
            *(unsigned int*)&bufA[b * STR + n0 + 2] = ((unsigned int)pb4[3] << 16) | pb4[2];
        }
        __syncthreads();
        for (int ki = 0; ki < 2; ++ki) {
            int poff = (mblk * 16 + lq) * STR + ki * 32 + quad * 8;
            short8 ap = *(const short8*)&bufA[poff];
            for (int j = 0; j < 2; ++j) {
                int doff = ((nt0 + j) * 16 + lq) * STR + ki * 32 + quad * 8;
                short8 bm = *(const short8*)&bufB[doff];
                Uacc[j] = __builtin_amdgcn_mfma_f32_16x16x32_bf16(ap, bm, Uacc[j], 0, 0, 0);
            }
        }
    }

    for (int j = 0; j < 2; ++j) {
        float v = lac[j];
        v += __shfl_xor(v, 16);
        v += __shfl_xor(v, 32);
        if (quad == 0) lsc[mblk][(nt0 + j) * 16 + lq] = v;
    }
    __syncthreads();
    float* pp = part + ((size_t)split * B_SZ + b0) * PSTRIDE;
    for (int j = 0; j < 2; ++j) {
        int d = (nt0 + j) * 16 + lq;
        if (d < D_SZ) {
#pragma unroll
            for (int r4 = 0; r4 < 4; ++r4) {
                int b = mblk * 16 + quad * 4 + r4;
                pp[(size_t)b * PSTRIDE + d] = Uacc[j][r4];
            }
        }
    }
    if (t < 64) {
        float Ls = lsc[0][t] + lsc[1][t] + lsc[2][t] + lsc[3][t];
        pp[(size_t)t * PSTRIDE + D_SZ] = Ls;
    }
}

// combine: 256 threads / 4 batch rows per block (was 64-thread blocks x 2048)
__global__ __launch_bounds__(256)
void combine(const float* __restrict__ x, const float* __restrict__ part,
             float* __restrict__ out, int nsplit) {
    const int b = blockIdx.x * 4 + (threadIdx.x >> 6);
    const int t = threadIdx.x & 63;
    float L = 0.f;
    for (int s = 0; s < nsplit; ++s)
        L += part[((size_t)s * B_SZ + b) * PSTRIDE + D_SZ];
    if (t < D_SZ) {
        float acc = 0.f;
        for (int s = 0; s < nsplit; ++s)
            acc += part[((size_t)s * B_SZ + b) * PSTRIDE + t];
        out[(size_t)b * (2 * D_SZ) + t] = x[(size_t)b * D_SZ + t];
        out[(size_t)b * (2 * D_SZ) + D_SZ + t] = acc / L;
    }
}

extern "C" void kernel_launch(void* const* d_in, const int* in_sizes, int n_in,
                              void* d_out, int out_size, void* d_ws, size_t ws_size,
                              hipStream_t stream) {
    const float* x = (const float*)d_in[0];
    const float* M = (const float*)d_in[1];
    float* out = (float*)d_out;
    const size_t per_split = (size_t)B_SZ * PSTRIDE * sizeof(float);

    if (ws_size >= IMG_BYTES + 8 * per_split) {
        unsigned short* img = (unsigned short*)d_ws;
        float* part = (float*)((char*)d_ws + IMG_BYTES);
        int ns = (int)((ws_size - IMG_BYTES) / per_split);
        if (ns > 32) ns = 32;
        ns &= ~7;                                          // multiple of 8 for XCD swizzle
        int slice = (((K_SZ + ns - 1) / ns) + 63) & ~63;   // 64-aligned splits
        precompute_m<<<NCH, 256, 0, stream>>>(M, img);
        attend_fast<<<32 * ns, 512, 0, stream>>>(x, img, part, slice);
        combine<<<B_SZ / 4, 256, 0, stream>>>(x, part, out, ns);
    } else {
        float* part = (float*)d_ws;
        int ns = (int)(ws_size / per_split);
        if (ns > 32) ns = 32;
        if (ns < 1) ns = 1;
        int slice = (K_SZ + ns - 1) / ns;
        dim3 gridA(B_SZ / 64, ns);
        attend_partial_v2<<<gridA, 512, 0, stream>>>(x, M, part, slice);
        combine<<<B_SZ / 4, 256, 0, stream>>>(x, part, out, ns);
    }
}